// Round 1
// baseline (730.961 us; speedup 1.0000x reference)
//
#include <hip/hip_runtime.h>

// Problem constants (from the reference file)
#define N_NODES 50000
#define N_EDGES 800000
#define F_IN_D  128
#define H_DIM   256
#define L_DIM   64
#define G_NUM   500

// ---------------------------------------------------------------------------
// Graph preprocessing
// ---------------------------------------------------------------------------
__global__ void init_kernel(int* __restrict__ hist, int* __restrict__ cnt) {
    int i = blockIdx.x * 256 + threadIdx.x;
    if (i < N_NODES) hist[i] = 0;
    if (i < G_NUM)   cnt[i]  = 0;
}

__global__ void count_kernel(const int* __restrict__ dst, const int* __restrict__ batch,
                             int* __restrict__ hist, int* __restrict__ cnt) {
    int i = blockIdx.x * 256 + threadIdx.x;
    if (i < N_EDGES) atomicAdd(&hist[dst[i]], 1);
    if (i < N_NODES) atomicAdd(&cnt[batch[i]], 1);
}

__global__ void dinv_kernel(const int* __restrict__ hist, float* __restrict__ dinv) {
    int i = blockIdx.x * 256 + threadIdx.x;
    if (i < N_NODES) {
        float d = (float)(hist[i] + 1);   // +1 self loop; always >= 1
        dinv[i] = 1.0f / sqrtf(d);
    }
}

// Single-block exclusive scan (n up to ~50k; 1024 threads, chunked)
__global__ void scan_kernel(const int* __restrict__ in, int* __restrict__ out,
                            int* __restrict__ cursor, int n) {
    __shared__ int sm[1024];
    __shared__ int carry_s;
    if (threadIdx.x == 0) carry_s = 0;
    __syncthreads();
    for (int base = 0; base < n; base += 1024) {
        int i = base + (int)threadIdx.x;
        int v = (i < n) ? in[i] : 0;
        sm[threadIdx.x] = v;
        __syncthreads();
        for (int off = 1; off < 1024; off <<= 1) {
            int t = (threadIdx.x >= (unsigned)off) ? sm[threadIdx.x - off] : 0;
            __syncthreads();
            sm[threadIdx.x] += t;
            __syncthreads();
        }
        int excl = sm[threadIdx.x] - v + carry_s;
        if (i < n) {
            out[i] = excl;
            if (cursor) cursor[i] = excl;
        }
        __syncthreads();
        if (threadIdx.x == 1023) carry_s += sm[1023];
        __syncthreads();
    }
    if (threadIdx.x == 0) out[n] = carry_s;
}

__global__ void place_kernel(const int* __restrict__ src, const int* __restrict__ dst,
                             int* __restrict__ cursor, int* __restrict__ csr_src) {
    int e = blockIdx.x * 256 + threadIdx.x;
    if (e < N_EDGES) {
        int d = dst[e];
        int pos = atomicAdd(&cursor[d], 1);
        csr_src[pos] = src[e];
    }
}

// ---------------------------------------------------------------------------
// fp32 GEMM: C[M,256] = A[M,K] @ W[K,256].  Tile 64x128, BK=16, 256 threads.
// ---------------------------------------------------------------------------
template<int K>
__global__ __launch_bounds__(256)
void gemm_kernel(const float* __restrict__ A, const float* __restrict__ W,
                 float* __restrict__ C, int M) {
    const int BM = 64, BN = 128, BK = 16;
    __shared__ float As[BK][BM + 4];   // +4 pad: breaks 4-way write conflict
    __shared__ float Bs[BK][BN];
    int tid = threadIdx.x;
    int tx = tid & 15;          // col group: 8 cols each
    int ty = tid >> 4;          // row group: 4 rows each
    int m0 = blockIdx.x * BM;
    int n0 = blockIdx.y * BN;

    float acc[4][8];
#pragma unroll
    for (int i = 0; i < 4; ++i)
#pragma unroll
        for (int j = 0; j < 8; ++j) acc[i][j] = 0.0f;

    for (int k0 = 0; k0 < K; k0 += BK) {
        // A tile: 64x16, each thread a float4 along k, store transposed
        {
            int m  = tid >> 2;
            int kq = (tid & 3) * 4;
            float4 a = make_float4(0.f, 0.f, 0.f, 0.f);
            if (m0 + m < M)
                a = *(const float4*)&A[(size_t)(m0 + m) * K + k0 + kq];
            As[kq + 0][m] = a.x; As[kq + 1][m] = a.y;
            As[kq + 2][m] = a.z; As[kq + 3][m] = a.w;
        }
        // B tile: 16x128, each thread two float4
        {
            int kr = tid >> 4;           // 0..15
            int n  = (tid & 15) * 8;     // 0..120
            const float4* wp = (const float4*)&W[(size_t)(k0 + kr) * H_DIM + n0 + n];
            *(float4*)&Bs[kr][n]     = wp[0];
            *(float4*)&Bs[kr][n + 4] = wp[1];
        }
        __syncthreads();
#pragma unroll
        for (int kk = 0; kk < BK; ++kk) {
            float4 a4 = *(const float4*)&As[kk][ty * 4];
            float4 b0 = *(const float4*)&Bs[kk][tx * 8];
            float4 b1 = *(const float4*)&Bs[kk][tx * 8 + 4];
            float av[4] = {a4.x, a4.y, a4.z, a4.w};
            float bv[8] = {b0.x, b0.y, b0.z, b0.w, b1.x, b1.y, b1.z, b1.w};
#pragma unroll
            for (int i = 0; i < 4; ++i)
#pragma unroll
                for (int j = 0; j < 8; ++j)
                    acc[i][j] = fmaf(av[i], bv[j], acc[i][j]);
        }
        __syncthreads();
    }

#pragma unroll
    for (int i = 0; i < 4; ++i) {
        int m = m0 + ty * 4 + i;
        if (m < M) {
            float4 o0 = make_float4(acc[i][0], acc[i][1], acc[i][2], acc[i][3]);
            float4 o1 = make_float4(acc[i][4], acc[i][5], acc[i][6], acc[i][7]);
            *(float4*)&C[(size_t)m * H_DIM + n0 + tx * 8]     = o0;
            *(float4*)&C[(size_t)m * H_DIM + n0 + tx * 8 + 4] = o1;
        }
    }
}

// ---------------------------------------------------------------------------
// GCN aggregation: out[i] = relu(dinv[i]*(sum_{s in nbr(i)} dinv[s]*A[s]
//                                          + dinv[i]*A[i]) + bias)
// One wave per node, lane handles 4 contiguous cols (float4).
// ---------------------------------------------------------------------------
__global__ __launch_bounds__(256)
void agg_kernel(const float* __restrict__ Ain, const float* __restrict__ dinv,
                const int* __restrict__ row_ptr, const int* __restrict__ csr_src,
                const float* __restrict__ bias, float* __restrict__ Out) {
    int wave = threadIdx.x >> 6;
    int lane = threadIdx.x & 63;
    int node = blockIdx.x * 4 + wave;
    if (node >= N_NODES) return;
    int c = lane * 4;
    float di = dinv[node];
    int r0 = row_ptr[node], r1 = row_ptr[node + 1];

    float4 self = *(const float4*)&Ain[(size_t)node * H_DIM + c];
    float ax = di * self.x, ay = di * self.y, az = di * self.z, aw = di * self.w;
    for (int j = r0; j < r1; ++j) {
        int s   = csr_src[j];
        float w = dinv[s];
        float4 v = *(const float4*)&Ain[(size_t)s * H_DIM + c];
        ax = fmaf(w, v.x, ax); ay = fmaf(w, v.y, ay);
        az = fmaf(w, v.z, az); aw = fmaf(w, v.w, aw);
    }
    float4 bq = *(const float4*)&bias[c];
    float4 o;
    o.x = fmaxf(fmaf(di, ax, bq.x), 0.f);
    o.y = fmaxf(fmaf(di, ay, bq.y), 0.f);
    o.z = fmaxf(fmaf(di, az, bq.z), 0.f);
    o.w = fmaxf(fmaf(di, aw, bq.w), 0.f);
    *(float4*)&Out[(size_t)node * H_DIM + c] = o;
}

// ---------------------------------------------------------------------------
// Mean pool per graph (batch is sorted -> contiguous node ranges via goff)
// ---------------------------------------------------------------------------
__global__ void pool_kernel(const float* __restrict__ Hin, const int* __restrict__ goff,
                            float* __restrict__ pooled) {
    int g = blockIdx.x;
    int lane = threadIdx.x;     // 64
    int s = goff[g], e = goff[g + 1];
    int c = lane * 4;
    float ax = 0.f, ay = 0.f, az = 0.f, aw = 0.f;
    for (int i = s; i < e; ++i) {
        float4 v = *(const float4*)&Hin[(size_t)i * H_DIM + c];
        ax += v.x; ay += v.y; az += v.z; aw += v.w;
    }
    float inv = 1.0f / fmaxf((float)(e - s), 1.0f);
    float4 o = make_float4(ax * inv, ay * inv, az * inv, aw * inv);
    *(float4*)&pooled[(size_t)g * H_DIM + c] = o;
}

// ---------------------------------------------------------------------------
// Heads: mu = hg @ Wmu + bmu ; logvar = hg @ Wlv + blv  (256 -> 64)
// ---------------------------------------------------------------------------
__global__ void head_kernel(const float* __restrict__ pooled,
                            const float* __restrict__ Wmu, const float* __restrict__ bmu,
                            const float* __restrict__ Wlv, const float* __restrict__ blv,
                            float* __restrict__ out) {
    __shared__ float hg[H_DIM];
    int g = blockIdx.x, l = threadIdx.x;   // 64 threads
    for (int k = l; k < H_DIM; k += 64) hg[k] = pooled[(size_t)g * H_DIM + k];
    __syncthreads();
    float mu = bmu[l], lv = blv[l];
    for (int k = 0; k < H_DIM; ++k) {
        float h = hg[k];
        mu = fmaf(h, Wmu[k * L_DIM + l], mu);
        lv = fmaf(h, Wlv[k * L_DIM + l], lv);
    }
    out[(size_t)g * L_DIM + l] = mu;
    out[(size_t)G_NUM * L_DIM + (size_t)g * L_DIM + l] = lv;
}

// ---------------------------------------------------------------------------
extern "C" void kernel_launch(void* const* d_in, const int* in_sizes, int n_in,
                              void* d_out, int out_size, void* d_ws, size_t ws_size,
                              hipStream_t stream) {
    const float* x     = (const float*)d_in[0];
    const int*   ei    = (const int*)  d_in[1];
    const int*   batch = (const int*)  d_in[2];
    // d_in[3] = num_graphs scalar (known: G_NUM)
    const float* W1  = (const float*)d_in[4];
    const float* b1  = (const float*)d_in[5];
    const float* W2  = (const float*)d_in[6];
    const float* b2  = (const float*)d_in[7];
    const float* Wmu = (const float*)d_in[8];
    const float* bmu = (const float*)d_in[9];
    const float* Wlv = (const float*)d_in[10];
    const float* blv = (const float*)d_in[11];
    const int* src = ei;
    const int* dst = ei + N_EDGES;

    char* ws = (char*)d_ws;
    size_t off = 0;
    auto alloc = [&](size_t bytes) -> void* {
        void* p = ws + off;
        off += (bytes + 255) & ~(size_t)255;
        return p;
    };
    int*   hist    = (int*)  alloc((size_t)N_NODES * 4);
    int*   cnt     = (int*)  alloc((size_t)G_NUM * 4);
    float* dinv    = (float*)alloc((size_t)N_NODES * 4);
    int*   row_ptr = (int*)  alloc((size_t)(N_NODES + 1) * 4);
    int*   cursor  = (int*)  alloc((size_t)N_NODES * 4);
    int*   csr_src = (int*)  alloc((size_t)N_EDGES * 4);
    int*   goff    = (int*)  alloc((size_t)(G_NUM + 1) * 4);
    int*   gcur    = (int*)  alloc((size_t)G_NUM * 4);
    float* bufA    = (float*)alloc((size_t)N_NODES * H_DIM * 4);
    float* bufB    = (float*)alloc((size_t)N_NODES * H_DIM * 4);
    float* pooled  = (float*)alloc((size_t)G_NUM * H_DIM * 4);
    (void)ws_size; (void)n_in; (void)in_sizes; (void)out_size;

    init_kernel <<<(N_NODES + 255) / 256, 256, 0, stream>>>(hist, cnt);
    count_kernel<<<(N_EDGES + 255) / 256, 256, 0, stream>>>(dst, batch, hist, cnt);
    dinv_kernel <<<(N_NODES + 255) / 256, 256, 0, stream>>>(hist, dinv);
    scan_kernel <<<1, 1024, 0, stream>>>(hist, row_ptr, cursor, N_NODES);
    place_kernel<<<(N_EDGES + 255) / 256, 256, 0, stream>>>(src, dst, cursor, csr_src);
    scan_kernel <<<1, 1024, 0, stream>>>(cnt, goff, gcur, G_NUM);

    gemm_kernel<F_IN_D><<<dim3((N_NODES + 63) / 64, 2), 256, 0, stream>>>(x, W1, bufA, N_NODES);
    agg_kernel <<<(N_NODES + 3) / 4, 256, 0, stream>>>(bufA, dinv, row_ptr, csr_src, b1, bufB);
    gemm_kernel<H_DIM><<<dim3((N_NODES + 63) / 64, 2), 256, 0, stream>>>(bufB, W2, bufA, N_NODES);
    agg_kernel <<<(N_NODES + 3) / 4, 256, 0, stream>>>(bufA, dinv, row_ptr, csr_src, b2, bufB);

    pool_kernel<<<G_NUM, 64, 0, stream>>>(bufB, goff, pooled);
    head_kernel<<<G_NUM, 64, 0, stream>>>(pooled, Wmu, bmu, Wlv, blv, (float*)d_out);
}

// Round 2
// 535.955 us; speedup vs baseline: 1.3638x; 1.3638x over previous
//
#include <hip/hip_runtime.h>

// Problem constants (from the reference file)
#define N_NODES 50000
#define N_EDGES 800000
#define F_IN_D  128
#define H_DIM   256
#define L_DIM   64
#define G_NUM   500

typedef unsigned int   u32;
typedef unsigned short u16;
typedef __attribute__((ext_vector_type(8))) short short8;
typedef __attribute__((ext_vector_type(4))) float f32x4;

static __device__ __forceinline__ float bf2f(u16 u) {
    union { u32 i; float f; } x; x.i = ((u32)u) << 16; return x.f;
}
static __device__ __forceinline__ u16 f2bf(float f) {
    union { float f; u32 i; } x; x.f = f;
    u32 r = (x.i + 0x7fffu + ((x.i >> 16) & 1u)) >> 16;
    return (u16)r;
}

// ---------------------------------------------------------------------------
// Graph preprocessing
// ---------------------------------------------------------------------------
__global__ void init_kernel(int* __restrict__ hist, int* __restrict__ cnt) {
    int i = blockIdx.x * 256 + threadIdx.x;
    if (i < N_NODES) hist[i] = 0;
    if (i < G_NUM)   cnt[i]  = 0;
}

__global__ void count_kernel(const int* __restrict__ dst, const int* __restrict__ batch,
                             int* __restrict__ hist, int* __restrict__ cnt) {
    int i = blockIdx.x * 256 + threadIdx.x;
    if (i < N_EDGES) atomicAdd(&hist[dst[i]], 1);
    if (i < N_NODES) atomicAdd(&cnt[batch[i]], 1);
}

__global__ void dinv_kernel(const int* __restrict__ hist, float* __restrict__ dinv) {
    int i = blockIdx.x * 256 + threadIdx.x;
    if (i < N_NODES) {
        float d = (float)(hist[i] + 1);   // +1 self loop; always >= 1
        dinv[i] = 1.0f / sqrtf(d);
    }
}

// --------- hierarchical exclusive scan (n = 50000, chunk = 256) ------------
__global__ void scan_chunk_kernel(const int* __restrict__ in, int* __restrict__ excl,
                                  int* __restrict__ partials, int n) {
    __shared__ int sm[256];
    int t = threadIdx.x;
    int i = blockIdx.x * 256 + t;
    int v = (i < n) ? in[i] : 0;
    sm[t] = v; __syncthreads();
    for (int off = 1; off < 256; off <<= 1) {
        int x = (t >= off) ? sm[t - off] : 0;
        __syncthreads();
        sm[t] += x;
        __syncthreads();
    }
    if (i < n) excl[i] = sm[t] - v;
    if (t == 255) partials[blockIdx.x] = sm[255];
}

__global__ void scan_part_kernel(int* __restrict__ partials, int nb, int* __restrict__ total_out) {
    __shared__ int sm[256];
    int t = threadIdx.x;
    int v = (t < nb) ? partials[t] : 0;
    sm[t] = v; __syncthreads();
    for (int off = 1; off < 256; off <<= 1) {
        int x = (t >= off) ? sm[t - off] : 0;
        __syncthreads();
        sm[t] += x;
        __syncthreads();
    }
    if (t < nb) partials[t] = sm[t] - v;
    if (t == 255) *total_out = sm[255];
}

__global__ void scan_final_kernel(const int* __restrict__ excl, const int* __restrict__ partials,
                                  int* __restrict__ out, int* __restrict__ cursor, int n) {
    int i = blockIdx.x * 256 + threadIdx.x;
    if (i < n) {
        int v = excl[i] + partials[blockIdx.x];
        out[i] = v;
        cursor[i] = v;
    }
}

// single-block scan for graph counts (n <= 512)
__global__ __launch_bounds__(512)
void scan_small_kernel(const int* __restrict__ in, int* __restrict__ out, int n) {
    __shared__ int sm[512];
    int t = threadIdx.x;
    int v = (t < n) ? in[t] : 0;
    sm[t] = v; __syncthreads();
    for (int off = 1; off < 512; off <<= 1) {
        int x = (t >= off) ? sm[t - off] : 0;
        __syncthreads();
        sm[t] += x;
        __syncthreads();
    }
    if (t < n) out[t] = sm[t] - v;
    if (t == 511) out[n] = sm[511];
}

__global__ void place_kernel(const int* __restrict__ src, const int* __restrict__ dst,
                             int* __restrict__ cursor, int* __restrict__ csr_src) {
    int e = blockIdx.x * 256 + threadIdx.x;
    if (e < N_EDGES) {
        int d = dst[e];
        int pos = atomicAdd(&cursor[d], 1);
        csr_src[pos] = src[e];
    }
}

// ---------------------------------------------------------------------------
// Conversions
// ---------------------------------------------------------------------------
__global__ void xconv_kernel(const float* __restrict__ x, u16* __restrict__ xb) {
    int i = blockIdx.x * 256 + threadIdx.x;
    if ((size_t)i * 4 >= (size_t)N_NODES * F_IN_D) return;
    float4 v = *(const float4*)&x[(size_t)i * 4];
    ushort4 o;
    o.x = f2bf(v.x); o.y = f2bf(v.y); o.z = f2bf(v.z); o.w = f2bf(v.w);
    *(ushort4*)&xb[(size_t)i * 4] = o;
}

// W [K][256] fp32  ->  hi/lo bf16 transposed [256][K]
__global__ void wconv_kernel(const float* __restrict__ W, u16* __restrict__ hi,
                             u16* __restrict__ lo, int K) {
    int idx = blockIdx.x * 256 + threadIdx.x;
    if (idx >= K * 256) return;
    int k = idx >> 8;
    int n = idx & 255;
    float w = W[idx];
    u16 h = f2bf(w);
    u16 l = f2bf(w - bf2f(h));
    hi[n * K + k] = h;
    lo[n * K + k] = l;
}

// ---------------------------------------------------------------------------
// GCN aggregation (normalized adjacency), bf16 in -> bf16 out
//   out[i] = di * ( sum_{s in nbr(i)} dinv[s]*v[s] + di*v[i] )
// One wave per node.
// ---------------------------------------------------------------------------
__global__ __launch_bounds__(256)
void agg128_kernel(const u16* __restrict__ In, const float* __restrict__ dinv,
                   const int* __restrict__ rp, const int* __restrict__ cs,
                   u16* __restrict__ Out) {
    int node = blockIdx.x * 4 + (threadIdx.x >> 6);
    int lane = threadIdx.x & 63;
    if (node >= N_NODES) return;
    int c = lane * 2;
    float di = dinv[node];
    int r0 = rp[node], r1 = rp[node + 1];
    u32 sv = *(const u32*)&In[(size_t)node * 128 + c];
    float a0 = di * bf2f((u16)(sv & 0xffff));
    float a1 = di * bf2f((u16)(sv >> 16));
    for (int j = r0; j < r1; ++j) {
        int s = cs[j];
        float w = dinv[s];
        u32 v = *(const u32*)&In[(size_t)s * 128 + c];
        a0 = fmaf(w, bf2f((u16)(v & 0xffff)), a0);
        a1 = fmaf(w, bf2f((u16)(v >> 16)), a1);
    }
    u32 o = ((u32)f2bf(di * a1) << 16) | (u32)f2bf(di * a0);
    *(u32*)&Out[(size_t)node * 128 + c] = o;
}

__global__ __launch_bounds__(256)
void agg256_kernel(const u16* __restrict__ In, const float* __restrict__ dinv,
                   const int* __restrict__ rp, const int* __restrict__ cs,
                   u16* __restrict__ Out) {
    int node = blockIdx.x * 4 + (threadIdx.x >> 6);
    int lane = threadIdx.x & 63;
    if (node >= N_NODES) return;
    int c = lane * 4;
    float di = dinv[node];
    int r0 = rp[node], r1 = rp[node + 1];
    uint2 sv = *(const uint2*)&In[(size_t)node * 256 + c];
    float a0 = di * bf2f((u16)(sv.x & 0xffff));
    float a1 = di * bf2f((u16)(sv.x >> 16));
    float a2 = di * bf2f((u16)(sv.y & 0xffff));
    float a3 = di * bf2f((u16)(sv.y >> 16));
    for (int j = r0; j < r1; ++j) {
        int s = cs[j];
        float w = dinv[s];
        uint2 v = *(const uint2*)&In[(size_t)s * 256 + c];
        a0 = fmaf(w, bf2f((u16)(v.x & 0xffff)), a0);
        a1 = fmaf(w, bf2f((u16)(v.x >> 16)), a1);
        a2 = fmaf(w, bf2f((u16)(v.y & 0xffff)), a2);
        a3 = fmaf(w, bf2f((u16)(v.y >> 16)), a3);
    }
    uint2 o;
    o.x = ((u32)f2bf(di * a1) << 16) | (u32)f2bf(di * a0);
    o.y = ((u32)f2bf(di * a3) << 16) | (u32)f2bf(di * a2);
    *(uint2*)&Out[(size_t)node * 256 + c] = o;
}

// ---------------------------------------------------------------------------
// MFMA GEMM: Out[M,256] = relu( A[M,K](bf16) @ W[K,256] + bias ), bf16 out.
// W given as transposed bf16 planes Bhi/Blo [256][K] (W = hi + lo split).
// Block: 4 waves; block covers 32 rows x 256 cols; wave w covers cols w*64..+64.
// MFMA 16x16x32 bf16: A-frag lane(m=l&15, k=(l>>4)*8+j), B-frag lane(n=l&15,
// k=(l>>4)*8+j), C/D lane(col=l&15, row=(l>>4)*4+reg).
// ---------------------------------------------------------------------------
template<int K>
__global__ __launch_bounds__(256)
void gemm_mfma_kernel(const u16* __restrict__ A, const u16* __restrict__ Bhi,
                      const u16* __restrict__ Blo, const float* __restrict__ bias,
                      u16* __restrict__ Out, int M) {
    __shared__ u16 cst[32][264];   // +8 pad breaks write conflicts
    int tid  = threadIdx.x;
    int wave = tid >> 6, lane = tid & 63;
    int m0 = blockIdx.x * 32;
    int n0 = wave * 64;
    int lr = lane & 15;
    int lk = (lane >> 4) * 8;

    f32x4 acc[2][4];
#pragma unroll
    for (int i = 0; i < 2; ++i)
#pragma unroll
        for (int j = 0; j < 4; ++j) acc[i][j] = {0.f, 0.f, 0.f, 0.f};

    for (int k0 = 0; k0 < K; k0 += 32) {
        short8 a[2], bh[4], bl[4];
#pragma unroll
        for (int mt = 0; mt < 2; ++mt) {
            int m = m0 + mt * 16 + lr;
            if (m > M - 1) m = M - 1;          // clamp (junk rows masked at store)
            a[mt] = *(const short8*)&A[(size_t)m * K + k0 + lk];
        }
#pragma unroll
        for (int nt = 0; nt < 4; ++nt) {
            int n = n0 + nt * 16 + lr;
            bh[nt] = *(const short8*)&Bhi[(size_t)n * K + k0 + lk];
            bl[nt] = *(const short8*)&Blo[(size_t)n * K + k0 + lk];
        }
#pragma unroll
        for (int mt = 0; mt < 2; ++mt)
#pragma unroll
            for (int nt = 0; nt < 4; ++nt) {
                acc[mt][nt] = __builtin_amdgcn_mfma_f32_16x16x32_bf16(a[mt], bh[nt], acc[mt][nt], 0, 0, 0);
                acc[mt][nt] = __builtin_amdgcn_mfma_f32_16x16x32_bf16(a[mt], bl[nt], acc[mt][nt], 0, 0, 0);
            }
    }

    // epilogue: bias + relu + bf16, scatter into LDS, then coalesced store
#pragma unroll
    for (int mt = 0; mt < 2; ++mt)
#pragma unroll
        for (int nt = 0; nt < 4; ++nt) {
            int col = n0 + nt * 16 + lr;
            float b = bias[col];
#pragma unroll
            for (int r = 0; r < 4; ++r) {
                int row = mt * 16 + (lane >> 4) * 4 + r;
                float v = fmaxf(acc[mt][nt][r] + b, 0.f);
                cst[row][col] = f2bf(v);
            }
        }
    __syncthreads();
#pragma unroll
    for (int p = 0; p < 4; ++p) {
        int row = p * 8 + (tid >> 5);
        int c16 = (tid & 31) * 8;
        int m = m0 + row;
        if (m < M) {
            uint4 v = *(const uint4*)&cst[row][c16];
            *(uint4*)&Out[(size_t)m * 256 + c16] = v;
        }
    }
}

// ---------------------------------------------------------------------------
// Mean pool per graph (batch sorted -> contiguous ranges), bf16 in, fp32 out
// ---------------------------------------------------------------------------
__global__ void pool_kernel(const u16* __restrict__ H2, const int* __restrict__ goff,
                            float* __restrict__ pooled) {
    int g = blockIdx.x;
    int lane = threadIdx.x;     // 64
    int s = goff[g], e = goff[g + 1];
    int c = lane * 4;
    float a0 = 0.f, a1 = 0.f, a2 = 0.f, a3 = 0.f;
    for (int i = s; i < e; ++i) {
        uint2 v = *(const uint2*)&H2[(size_t)i * 256 + c];
        a0 += bf2f((u16)(v.x & 0xffff));
        a1 += bf2f((u16)(v.x >> 16));
        a2 += bf2f((u16)(v.y & 0xffff));
        a3 += bf2f((u16)(v.y >> 16));
    }
    float inv = 1.0f / fmaxf((float)(e - s), 1.0f);
    float4 o = make_float4(a0 * inv, a1 * inv, a2 * inv, a3 * inv);
    *(float4*)&pooled[(size_t)g * H_DIM + c] = o;
}

// ---------------------------------------------------------------------------
// Heads (fp32 exact): mu = hg @ Wmu + bmu ; logvar = hg @ Wlv + blv
// ---------------------------------------------------------------------------
__global__ void head_kernel(const float* __restrict__ pooled,
                            const float* __restrict__ Wmu, const float* __restrict__ bmu,
                            const float* __restrict__ Wlv, const float* __restrict__ blv,
                            float* __restrict__ out) {
    __shared__ float hg[H_DIM];
    int g = blockIdx.x, l = threadIdx.x;   // 64 threads
    for (int k = l; k < H_DIM; k += 64) hg[k] = pooled[(size_t)g * H_DIM + k];
    __syncthreads();
    float mu = bmu[l], lv = blv[l];
    for (int k = 0; k < H_DIM; ++k) {
        float h = hg[k];
        mu = fmaf(h, Wmu[k * L_DIM + l], mu);
        lv = fmaf(h, Wlv[k * L_DIM + l], lv);
    }
    out[(size_t)g * L_DIM + l] = mu;
    out[(size_t)G_NUM * L_DIM + (size_t)g * L_DIM + l] = lv;
}

// ---------------------------------------------------------------------------
extern "C" void kernel_launch(void* const* d_in, const int* in_sizes, int n_in,
                              void* d_out, int out_size, void* d_ws, size_t ws_size,
                              hipStream_t stream) {
    const float* x     = (const float*)d_in[0];
    const int*   ei    = (const int*)  d_in[1];
    const int*   batch = (const int*)  d_in[2];
    const float* W1  = (const float*)d_in[4];
    const float* b1  = (const float*)d_in[5];
    const float* W2  = (const float*)d_in[6];
    const float* b2  = (const float*)d_in[7];
    const float* Wmu = (const float*)d_in[8];
    const float* bmu = (const float*)d_in[9];
    const float* Wlv = (const float*)d_in[10];
    const float* blv = (const float*)d_in[11];
    const int* src = ei;
    const int* dst = ei + N_EDGES;

    char* ws = (char*)d_ws;
    size_t off = 0;
    auto alloc = [&](size_t bytes) -> void* {
        void* p = ws + off;
        off += (bytes + 255) & ~(size_t)255;
        return p;
    };
    int*   hist     = (int*)alloc((size_t)N_NODES * 4);
    int*   cnt      = (int*)alloc((size_t)G_NUM * 4);
    float* dinv     = (float*)alloc((size_t)N_NODES * 4);
    int*   row_ptr  = (int*)alloc((size_t)(N_NODES + 1) * 4);
    int*   cursor   = (int*)alloc((size_t)N_NODES * 4);
    int*   csr_src  = (int*)alloc((size_t)N_EDGES * 4);
    int*   goff     = (int*)alloc((size_t)(G_NUM + 1) * 4);
    int*   excl     = (int*)alloc((size_t)N_NODES * 4);
    int*   partials = (int*)alloc(256 * 4);
    u16*   xb   = (u16*)alloc((size_t)N_NODES * F_IN_D * 2);  // 12.8 MB
    u16*   Xa   = (u16*)alloc((size_t)N_NODES * F_IN_D * 2);  // 12.8 MB
    u16*   H1   = (u16*)alloc((size_t)N_NODES * H_DIM * 2);   // 25.6 MB
    u16*   Ha   = (u16*)alloc((size_t)N_NODES * H_DIM * 2);   // 25.6 MB
    u16*   w1hi = (u16*)alloc((size_t)F_IN_D * H_DIM * 2);
    u16*   w1lo = (u16*)alloc((size_t)F_IN_D * H_DIM * 2);
    u16*   w2hi = (u16*)alloc((size_t)H_DIM * H_DIM * 2);
    u16*   w2lo = (u16*)alloc((size_t)H_DIM * H_DIM * 2);
    float* pooled = (float*)alloc((size_t)G_NUM * H_DIM * 4);
    // H2 reuses xb+Xa region (both dead after gemm1): 25.6 MB, contiguous
    u16*   H2 = xb;
    (void)ws_size; (void)n_in; (void)in_sizes; (void)out_size;

    const int NB_SCAN = (N_NODES + 255) / 256;   // 196

    init_kernel <<<(N_NODES + 255) / 256, 256, 0, stream>>>(hist, cnt);
    count_kernel<<<(N_EDGES + 255) / 256, 256, 0, stream>>>(dst, batch, hist, cnt);
    dinv_kernel <<<(N_NODES + 255) / 256, 256, 0, stream>>>(hist, dinv);
    scan_chunk_kernel<<<NB_SCAN, 256, 0, stream>>>(hist, excl, partials, N_NODES);
    scan_part_kernel <<<1, 256, 0, stream>>>(partials, NB_SCAN, row_ptr + N_NODES);
    scan_final_kernel<<<NB_SCAN, 256, 0, stream>>>(excl, partials, row_ptr, cursor, N_NODES);
    place_kernel<<<(N_EDGES + 255) / 256, 256, 0, stream>>>(src, dst, cursor, csr_src);
    scan_small_kernel<<<1, 512, 0, stream>>>(cnt, goff, G_NUM);

    xconv_kernel<<<(N_NODES * F_IN_D / 4 + 255) / 256, 256, 0, stream>>>(x, xb);
    wconv_kernel<<<(F_IN_D * H_DIM + 255) / 256, 256, 0, stream>>>(W1, w1hi, w1lo, F_IN_D);
    wconv_kernel<<<(H_DIM * H_DIM + 255) / 256, 256, 0, stream>>>(W2, w2hi, w2lo, H_DIM);

    // layer 1: aggregate(x) then GEMM (A_hat (X W) == (A_hat X) W)
    agg128_kernel<<<(N_NODES + 3) / 4, 256, 0, stream>>>(xb, dinv, row_ptr, csr_src, Xa);
    gemm_mfma_kernel<F_IN_D><<<(N_NODES + 31) / 32, 256, 0, stream>>>(Xa, w1hi, w1lo, b1, H1, N_NODES);
    // layer 2
    agg256_kernel<<<(N_NODES + 3) / 4, 256, 0, stream>>>(H1, dinv, row_ptr, csr_src, Ha);
    gemm_mfma_kernel<H_DIM><<<(N_NODES + 31) / 32, 256, 0, stream>>>(Ha, w2hi, w2lo, b2, H2, N_NODES);

    pool_kernel<<<G_NUM, 64, 0, stream>>>(H2, goff, pooled);
    head_kernel<<<G_NUM, 64, 0, stream>>>(pooled, Wmu, bmu, Wlv, blv, (float*)d_out);
}

// Round 3
// 421.706 us; speedup vs baseline: 1.7333x; 1.2709x over previous
//
#include <hip/hip_runtime.h>

// Problem constants (from the reference file)
#define N_NODES 50000
#define N_EDGES 800000
#define F_IN_D  128
#define H_DIM   256
#define L_DIM   64
#define G_NUM   500

typedef unsigned int   u32;
typedef unsigned short u16;
typedef __attribute__((ext_vector_type(8))) short short8;
typedef __attribute__((ext_vector_type(4))) float f32x4;

static __device__ __forceinline__ float bf2f(u16 u) {
    union { u32 i; float f; } x; x.i = ((u32)u) << 16; return x.f;
}
static __device__ __forceinline__ u16 f2bf(float f) {
    union { float f; u32 i; } x; x.f = f;
    u32 r = (x.i + 0x7fffu + ((x.i >> 16) & 1u)) >> 16;
    return (u16)r;
}

// ---------------------------------------------------------------------------
// Graph preprocessing
// ---------------------------------------------------------------------------
__global__ void init_kernel(int* __restrict__ hist, int* __restrict__ cnt,
                            float* __restrict__ pooled) {
    int i = blockIdx.x * 256 + threadIdx.x;
    if (i < N_NODES) hist[i] = 0;
    if (i < G_NUM)   cnt[i]  = 0;
    if (i < G_NUM * H_DIM) pooled[i] = 0.f;
}

__global__ void count_kernel(const int* __restrict__ dst, const int* __restrict__ batch,
                             int* __restrict__ hist, int* __restrict__ cnt) {
    int i = blockIdx.x * 256 + threadIdx.x;
    if (i < N_EDGES) atomicAdd(&hist[dst[i]], 1);
    if (i < N_NODES) atomicAdd(&cnt[batch[i]], 1);
}

// exclusive scan of hist (chunk=256) + fused dinv computation
__global__ void scan_chunk_kernel(const int* __restrict__ in, int* __restrict__ excl,
                                  int* __restrict__ partials, float* __restrict__ dinv, int n) {
    __shared__ int sm[256];
    int t = threadIdx.x;
    int i = blockIdx.x * 256 + t;
    int v = (i < n) ? in[i] : 0;
    sm[t] = v; __syncthreads();
    for (int off = 1; off < 256; off <<= 1) {
        int x = (t >= off) ? sm[t - off] : 0;
        __syncthreads();
        sm[t] += x;
        __syncthreads();
    }
    if (i < n) {
        excl[i] = sm[t] - v;
        dinv[i] = 1.0f / sqrtf((float)(v + 1));   // +1 self loop
    }
    if (t == 255) partials[blockIdx.x] = sm[255];
}

__global__ void scan_part_kernel(int* __restrict__ partials, int nb, int* __restrict__ total_out) {
    __shared__ int sm[256];
    int t = threadIdx.x;
    int v = (t < nb) ? partials[t] : 0;
    sm[t] = v; __syncthreads();
    for (int off = 1; off < 256; off <<= 1) {
        int x = (t >= off) ? sm[t - off] : 0;
        __syncthreads();
        sm[t] += x;
        __syncthreads();
    }
    if (t < nb) partials[t] = sm[t] - v;
    if (t == 255) *total_out = sm[255];
}

__global__ void scan_final_kernel(const int* __restrict__ excl, const int* __restrict__ partials,
                                  int* __restrict__ out, int* __restrict__ cursor, int n) {
    int i = blockIdx.x * 256 + threadIdx.x;
    if (i < n) {
        int v = excl[i] + partials[blockIdx.x];
        out[i] = v;
        cursor[i] = v;
    }
}

// CSR entries packed (src, bits(dinv[src])) -> one broadcast load per edge later
__global__ void place_kernel(const int* __restrict__ src, const int* __restrict__ dst,
                             const float* __restrict__ dinv,
                             int* __restrict__ cursor, uint2* __restrict__ csr) {
    int e = blockIdx.x * 256 + threadIdx.x;
    if (e < N_EDGES) {
        int s = src[e];
        int d = dst[e];
        int pos = atomicAdd(&cursor[d], 1);
        csr[pos] = make_uint2((u32)s, __float_as_uint(dinv[s]));
    }
}

// ---------------------------------------------------------------------------
// All dtype conversions in one launch:
//  seg0: x fp32 -> xb bf16 (float4 groups)
//  seg1: W1 [128][256] -> w1hi/w1lo transposed [256][128]
//  seg2: W2 [256][256] -> w2hi/w2lo transposed [256][256]
// ---------------------------------------------------------------------------
#define NXQ (N_NODES * F_IN_D / 4)          // 1,600,000
#define NW1 (F_IN_D * H_DIM)                // 32,768
#define NW2 (H_DIM * H_DIM)                 // 65,536
__global__ void conv_kernel(const float* __restrict__ x, u16* __restrict__ xb,
                            const float* __restrict__ W1, u16* __restrict__ w1hi, u16* __restrict__ w1lo,
                            const float* __restrict__ W2, u16* __restrict__ w2hi, u16* __restrict__ w2lo) {
    int i = blockIdx.x * 256 + threadIdx.x;
    if (i < NXQ) {
        float4 v = *(const float4*)&x[(size_t)i * 4];
        ushort4 o;
        o.x = f2bf(v.x); o.y = f2bf(v.y); o.z = f2bf(v.z); o.w = f2bf(v.w);
        *(ushort4*)&xb[(size_t)i * 4] = o;
    } else if (i < NXQ + NW1) {
        int idx = i - NXQ;
        int k = idx >> 8, n = idx & 255;
        float w = W1[idx];
        u16 h = f2bf(w);
        w1hi[n * F_IN_D + k] = h;
        w1lo[n * F_IN_D + k] = f2bf(w - bf2f(h));
    } else if (i < NXQ + NW1 + NW2) {
        int idx = i - NXQ - NW1;
        int k = idx >> 8, n = idx & 255;
        float w = W2[idx];
        u16 h = f2bf(w);
        w2hi[n * H_DIM + k] = h;
        w2lo[n * H_DIM + k] = f2bf(w - bf2f(h));
    }
}

// ---------------------------------------------------------------------------
// GCN aggregation, bf16 in -> bf16 out. One wave per node, edge loop
// unrolled x4 so 4 gathers are in flight (latency was the round-2 limiter).
// ---------------------------------------------------------------------------
__global__ __launch_bounds__(256)
void agg128_kernel(const u16* __restrict__ In, const float* __restrict__ dinv,
                   const int* __restrict__ rp, const uint2* __restrict__ csr,
                   u16* __restrict__ Out) {
    int node = blockIdx.x * 4 + (threadIdx.x >> 6);
    int lane = threadIdx.x & 63;
    if (node >= N_NODES) return;
    int c = lane * 2;
    float di = dinv[node];
    int r0 = rp[node], r1 = rp[node + 1];
    u32 sv = *(const u32*)&In[(size_t)node * 128 + c];
    float a0 = di * bf2f((u16)(sv & 0xffff));
    float a1 = di * bf2f((u16)(sv >> 16));
    int j = r0;
    for (; j + 4 <= r1; j += 4) {
        uint2 e0 = csr[j], e1 = csr[j + 1], e2 = csr[j + 2], e3 = csr[j + 3];
        u32 v0 = *(const u32*)&In[(size_t)e0.x * 128 + c];
        u32 v1 = *(const u32*)&In[(size_t)e1.x * 128 + c];
        u32 v2 = *(const u32*)&In[(size_t)e2.x * 128 + c];
        u32 v3 = *(const u32*)&In[(size_t)e3.x * 128 + c];
        float w0 = __uint_as_float(e0.y), w1 = __uint_as_float(e1.y);
        float w2 = __uint_as_float(e2.y), w3 = __uint_as_float(e3.y);
        a0 = fmaf(w0, bf2f((u16)(v0 & 0xffff)), a0);
        a1 = fmaf(w0, bf2f((u16)(v0 >> 16)), a1);
        a0 = fmaf(w1, bf2f((u16)(v1 & 0xffff)), a0);
        a1 = fmaf(w1, bf2f((u16)(v1 >> 16)), a1);
        a0 = fmaf(w2, bf2f((u16)(v2 & 0xffff)), a0);
        a1 = fmaf(w2, bf2f((u16)(v2 >> 16)), a1);
        a0 = fmaf(w3, bf2f((u16)(v3 & 0xffff)), a0);
        a1 = fmaf(w3, bf2f((u16)(v3 >> 16)), a1);
    }
    for (; j < r1; ++j) {
        uint2 e = csr[j];
        u32 v = *(const u32*)&In[(size_t)e.x * 128 + c];
        float w = __uint_as_float(e.y);
        a0 = fmaf(w, bf2f((u16)(v & 0xffff)), a0);
        a1 = fmaf(w, bf2f((u16)(v >> 16)), a1);
    }
    u32 o = ((u32)f2bf(di * a1) << 16) | (u32)f2bf(di * a0);
    *(u32*)&Out[(size_t)node * 128 + c] = o;
}

__global__ __launch_bounds__(256)
void agg256_kernel(const u16* __restrict__ In, const float* __restrict__ dinv,
                   const int* __restrict__ rp, const uint2* __restrict__ csr,
                   u16* __restrict__ Out) {
    int node = blockIdx.x * 4 + (threadIdx.x >> 6);
    int lane = threadIdx.x & 63;
    if (node >= N_NODES) return;
    int c = lane * 4;
    float di = dinv[node];
    int r0 = rp[node], r1 = rp[node + 1];
    uint2 sv = *(const uint2*)&In[(size_t)node * 256 + c];
    float a0 = di * bf2f((u16)(sv.x & 0xffff));
    float a1 = di * bf2f((u16)(sv.x >> 16));
    float a2 = di * bf2f((u16)(sv.y & 0xffff));
    float a3 = di * bf2f((u16)(sv.y >> 16));
    int j = r0;
    for (; j + 4 <= r1; j += 4) {
        uint2 e0 = csr[j], e1 = csr[j + 1], e2 = csr[j + 2], e3 = csr[j + 3];
        uint2 v0 = *(const uint2*)&In[(size_t)e0.x * 256 + c];
        uint2 v1 = *(const uint2*)&In[(size_t)e1.x * 256 + c];
        uint2 v2 = *(const uint2*)&In[(size_t)e2.x * 256 + c];
        uint2 v3 = *(const uint2*)&In[(size_t)e3.x * 256 + c];
        float w0 = __uint_as_float(e0.y), w1 = __uint_as_float(e1.y);
        float w2 = __uint_as_float(e2.y), w3 = __uint_as_float(e3.y);
        a0 = fmaf(w0, bf2f((u16)(v0.x & 0xffff)), a0);
        a1 = fmaf(w0, bf2f((u16)(v0.x >> 16)), a1);
        a2 = fmaf(w0, bf2f((u16)(v0.y & 0xffff)), a2);
        a3 = fmaf(w0, bf2f((u16)(v0.y >> 16)), a3);
        a0 = fmaf(w1, bf2f((u16)(v1.x & 0xffff)), a0);
        a1 = fmaf(w1, bf2f((u16)(v1.x >> 16)), a1);
        a2 = fmaf(w1, bf2f((u16)(v1.y & 0xffff)), a2);
        a3 = fmaf(w1, bf2f((u16)(v1.y >> 16)), a3);
        a0 = fmaf(w2, bf2f((u16)(v2.x & 0xffff)), a0);
        a1 = fmaf(w2, bf2f((u16)(v2.x >> 16)), a1);
        a2 = fmaf(w2, bf2f((u16)(v2.y & 0xffff)), a2);
        a3 = fmaf(w2, bf2f((u16)(v2.y >> 16)), a3);
        a0 = fmaf(w3, bf2f((u16)(v3.x & 0xffff)), a0);
        a1 = fmaf(w3, bf2f((u16)(v3.x >> 16)), a1);
        a2 = fmaf(w3, bf2f((u16)(v3.y & 0xffff)), a2);
        a3 = fmaf(w3, bf2f((u16)(v3.y >> 16)), a3);
    }
    for (; j < r1; ++j) {
        uint2 e = csr[j];
        uint2 v = *(const uint2*)&In[(size_t)e.x * 256 + c];
        float w = __uint_as_float(e.y);
        a0 = fmaf(w, bf2f((u16)(v.x & 0xffff)), a0);
        a1 = fmaf(w, bf2f((u16)(v.x >> 16)), a1);
        a2 = fmaf(w, bf2f((u16)(v.y & 0xffff)), a2);
        a3 = fmaf(w, bf2f((u16)(v.y >> 16)), a3);
    }
    uint2 o;
    o.x = ((u32)f2bf(di * a1) << 16) | (u32)f2bf(di * a0);
    o.y = ((u32)f2bf(di * a3) << 16) | (u32)f2bf(di * a2);
    *(uint2*)&Out[(size_t)node * 256 + c] = o;
}

// ---------------------------------------------------------------------------
// MFMA GEMM layer 1: H1[M,256] = relu( A[M,128] @ W1 + b1 ), bf16 out.
// W split into hi+lo bf16 planes (transposed [256][K]).
// ---------------------------------------------------------------------------
__global__ __launch_bounds__(256)
void gemm1_kernel(const u16* __restrict__ A, const u16* __restrict__ Bhi,
                  const u16* __restrict__ Blo, const float* __restrict__ bias,
                  u16* __restrict__ Out, int M) {
    const int K = F_IN_D;
    __shared__ u16 cst[32][264];
    int tid  = threadIdx.x;
    int wave = tid >> 6, lane = tid & 63;
    int m0 = blockIdx.x * 32;
    int n0 = wave * 64;
    int lr = lane & 15;
    int lk = (lane >> 4) * 8;

    f32x4 acc[2][4];
#pragma unroll
    for (int i = 0; i < 2; ++i)
#pragma unroll
        for (int j = 0; j < 4; ++j) acc[i][j] = {0.f, 0.f, 0.f, 0.f};

    for (int k0 = 0; k0 < K; k0 += 32) {
        short8 a[2], bh[4], bl[4];
#pragma unroll
        for (int mt = 0; mt < 2; ++mt) {
            int m = m0 + mt * 16 + lr;
            if (m > M - 1) m = M - 1;
            a[mt] = *(const short8*)&A[(size_t)m * K + k0 + lk];
        }
#pragma unroll
        for (int nt = 0; nt < 4; ++nt) {
            int n = n0 + nt * 16 + lr;
            bh[nt] = *(const short8*)&Bhi[(size_t)n * K + k0 + lk];
            bl[nt] = *(const short8*)&Blo[(size_t)n * K + k0 + lk];
        }
#pragma unroll
        for (int mt = 0; mt < 2; ++mt)
#pragma unroll
            for (int nt = 0; nt < 4; ++nt) {
                acc[mt][nt] = __builtin_amdgcn_mfma_f32_16x16x32_bf16(a[mt], bh[nt], acc[mt][nt], 0, 0, 0);
                acc[mt][nt] = __builtin_amdgcn_mfma_f32_16x16x32_bf16(a[mt], bl[nt], acc[mt][nt], 0, 0, 0);
            }
    }

#pragma unroll
    for (int mt = 0; mt < 2; ++mt)
#pragma unroll
        for (int nt = 0; nt < 4; ++nt) {
            int col = n0 + nt * 16 + lr;
            float b = bias[col];
#pragma unroll
            for (int r = 0; r < 4; ++r) {
                int row = mt * 16 + (lane >> 4) * 4 + r;
                cst[row][col] = f2bf(fmaxf(acc[mt][nt][r] + b, 0.f));
            }
        }
    __syncthreads();
#pragma unroll
    for (int p = 0; p < 4; ++p) {
        int row = p * 8 + (tid >> 5);
        int c16 = (tid & 31) * 8;
        int m = m0 + row;
        if (m < M) {
            uint4 v = *(const uint4*)&cst[row][c16];
            *(uint4*)&Out[(size_t)m * 256 + c16] = v;
        }
    }
}

// ---------------------------------------------------------------------------
// MFMA GEMM layer 2 with fused mean-pool accumulation:
//   H2 = relu( A[M,256] @ W2 + b2 )  (fp32, kept in LDS only)
//   pooled[g] += segment-sum of H2 rows (batch sorted -> per-block segments)
// No H2 global round-trip.
// ---------------------------------------------------------------------------
__global__ __launch_bounds__(256)
void gemm2_pool_kernel(const u16* __restrict__ A, const u16* __restrict__ Bhi,
                       const u16* __restrict__ Blo, const float* __restrict__ bias,
                       const int* __restrict__ batch, float* __restrict__ pooled, int M) {
    const int K = H_DIM;
    __shared__ float cst[32][260];
    __shared__ int batch_s[32];
    int tid  = threadIdx.x;
    int wave = tid >> 6, lane = tid & 63;
    int m0 = blockIdx.x * 32;
    int n0 = wave * 64;
    int lr = lane & 15;
    int lk = (lane >> 4) * 8;

    f32x4 acc[2][4];
#pragma unroll
    for (int i = 0; i < 2; ++i)
#pragma unroll
        for (int j = 0; j < 4; ++j) acc[i][j] = {0.f, 0.f, 0.f, 0.f};

    for (int k0 = 0; k0 < K; k0 += 32) {
        short8 a[2], bh[4], bl[4];
#pragma unroll
        for (int mt = 0; mt < 2; ++mt) {
            int m = m0 + mt * 16 + lr;
            if (m > M - 1) m = M - 1;
            a[mt] = *(const short8*)&A[(size_t)m * K + k0 + lk];
        }
#pragma unroll
        for (int nt = 0; nt < 4; ++nt) {
            int n = n0 + nt * 16 + lr;
            bh[nt] = *(const short8*)&Bhi[(size_t)n * K + k0 + lk];
            bl[nt] = *(const short8*)&Blo[(size_t)n * K + k0 + lk];
        }
#pragma unroll
        for (int mt = 0; mt < 2; ++mt)
#pragma unroll
            for (int nt = 0; nt < 4; ++nt) {
                acc[mt][nt] = __builtin_amdgcn_mfma_f32_16x16x32_bf16(a[mt], bh[nt], acc[mt][nt], 0, 0, 0);
                acc[mt][nt] = __builtin_amdgcn_mfma_f32_16x16x32_bf16(a[mt], bl[nt], acc[mt][nt], 0, 0, 0);
            }
    }

    if (tid < 32) {
        int m = m0 + tid;
        batch_s[tid] = (m < M) ? batch[m] : -1;
    }
#pragma unroll
    for (int mt = 0; mt < 2; ++mt)
#pragma unroll
        for (int nt = 0; nt < 4; ++nt) {
            int col = n0 + nt * 16 + lr;
            float b = bias[col];
#pragma unroll
            for (int r = 0; r < 4; ++r) {
                int row = mt * 16 + (lane >> 4) * 4 + r;
                cst[row][col] = fmaxf(acc[mt][nt][r] + b, 0.f);
            }
        }
    __syncthreads();

    // segmented pooling: thread = column, walk the 32 sorted rows
    int rows = M - m0; if (rows > 32) rows = 32;
    float s = 0.f;
    int gp = batch_s[0];
    for (int r = 0; r < rows; ++r) {
        int g = batch_s[r];
        if (g != gp) {
            atomicAdd(&pooled[(size_t)gp * H_DIM + tid], s);
            s = 0.f;
            gp = g;
        }
        s += cst[r][tid];
    }
    atomicAdd(&pooled[(size_t)gp * H_DIM + tid], s);
}

// ---------------------------------------------------------------------------
// Heads (fp32): h_graph = pooled/cnt; mu/logvar = h_graph @ W + b
// ---------------------------------------------------------------------------
__global__ void head_kernel(const float* __restrict__ pooled, const int* __restrict__ cnt,
                            const float* __restrict__ Wmu, const float* __restrict__ bmu,
                            const float* __restrict__ Wlv, const float* __restrict__ blv,
                            float* __restrict__ out) {
    __shared__ float hg[H_DIM];
    int g = blockIdx.x, l = threadIdx.x;   // 64 threads
    float inv = 1.0f / fmaxf((float)cnt[g], 1.0f);
    for (int k = l; k < H_DIM; k += 64) hg[k] = pooled[(size_t)g * H_DIM + k] * inv;
    __syncthreads();
    float mu = bmu[l], lv = blv[l];
    for (int k = 0; k < H_DIM; ++k) {
        float h = hg[k];
        mu = fmaf(h, Wmu[k * L_DIM + l], mu);
        lv = fmaf(h, Wlv[k * L_DIM + l], lv);
    }
    out[(size_t)g * L_DIM + l] = mu;
    out[(size_t)G_NUM * L_DIM + (size_t)g * L_DIM + l] = lv;
}

// ---------------------------------------------------------------------------
extern "C" void kernel_launch(void* const* d_in, const int* in_sizes, int n_in,
                              void* d_out, int out_size, void* d_ws, size_t ws_size,
                              hipStream_t stream) {
    const float* x     = (const float*)d_in[0];
    const int*   ei    = (const int*)  d_in[1];
    const int*   batch = (const int*)  d_in[2];
    const float* W1  = (const float*)d_in[4];
    const float* b1  = (const float*)d_in[5];
    const float* W2  = (const float*)d_in[6];
    const float* b2  = (const float*)d_in[7];
    const float* Wmu = (const float*)d_in[8];
    const float* bmu = (const float*)d_in[9];
    const float* Wlv = (const float*)d_in[10];
    const float* blv = (const float*)d_in[11];
    const int* src = ei;
    const int* dst = ei + N_EDGES;

    char* ws = (char*)d_ws;
    size_t off = 0;
    auto alloc = [&](size_t bytes) -> void* {
        void* p = ws + off;
        off += (bytes + 255) & ~(size_t)255;
        return p;
    };
    int*   hist     = (int*)alloc((size_t)N_NODES * 4);
    int*   cnt      = (int*)alloc((size_t)G_NUM * 4);
    float* dinv     = (float*)alloc((size_t)N_NODES * 4);
    int*   row_ptr  = (int*)alloc((size_t)(N_NODES + 1) * 4);
    int*   cursor   = (int*)alloc((size_t)N_NODES * 4);
    uint2* csr      = (uint2*)alloc((size_t)N_EDGES * 8);
    int*   excl     = (int*)alloc((size_t)N_NODES * 4);
    int*   partials = (int*)alloc(256 * 4);
    u16*   xb   = (u16*)alloc((size_t)N_NODES * F_IN_D * 2);  // 12.8 MB
    u16*   Xa   = (u16*)alloc((size_t)N_NODES * F_IN_D * 2);  // 12.8 MB
    u16*   H1   = (u16*)alloc((size_t)N_NODES * H_DIM * 2);   // 25.6 MB
    u16*   Ha   = (u16*)alloc((size_t)N_NODES * H_DIM * 2);   // 25.6 MB
    u16*   w1hi = (u16*)alloc((size_t)F_IN_D * H_DIM * 2);
    u16*   w1lo = (u16*)alloc((size_t)F_IN_D * H_DIM * 2);
    u16*   w2hi = (u16*)alloc((size_t)H_DIM * H_DIM * 2);
    u16*   w2lo = (u16*)alloc((size_t)H_DIM * H_DIM * 2);
    float* pooled = (float*)alloc((size_t)G_NUM * H_DIM * 4);
    (void)ws_size; (void)n_in; (void)in_sizes; (void)out_size;

    const int NB_SCAN = (N_NODES + 255) / 256;   // 196
    const int GEMM_NB = (N_NODES + 31) / 32;     // 1563

    init_kernel <<<512, 256, 0, stream>>>(hist, cnt, pooled);
    count_kernel<<<(N_EDGES + 255) / 256, 256, 0, stream>>>(dst, batch, hist, cnt);
    scan_chunk_kernel<<<NB_SCAN, 256, 0, stream>>>(hist, excl, partials, dinv, N_NODES);
    scan_part_kernel <<<1, 256, 0, stream>>>(partials, NB_SCAN, row_ptr + N_NODES);
    scan_final_kernel<<<NB_SCAN, 256, 0, stream>>>(excl, partials, row_ptr, cursor, N_NODES);
    place_kernel<<<(N_EDGES + 255) / 256, 256, 0, stream>>>(src, dst, dinv, cursor, csr);
    conv_kernel <<<(NXQ + NW1 + NW2 + 255) / 256, 256, 0, stream>>>(x, xb, W1, w1hi, w1lo, W2, w2hi, w2lo);

    // layer 1: aggregate(x) then GEMM  (A_hat (X W) == (A_hat X) W)
    agg128_kernel<<<(N_NODES + 3) / 4, 256, 0, stream>>>(xb, dinv, row_ptr, csr, Xa);
    gemm1_kernel <<<GEMM_NB, 256, 0, stream>>>(Xa, w1hi, w1lo, b1, H1, N_NODES);
    // layer 2: aggregate(H1) then GEMM with fused mean-pool
    agg256_kernel<<<(N_NODES + 3) / 4, 256, 0, stream>>>(H1, dinv, row_ptr, csr, Ha);
    gemm2_pool_kernel<<<GEMM_NB, 256, 0, stream>>>(Ha, w2hi, w2lo, b2, batch, pooled, N_NODES);

    head_kernel<<<G_NUM, 64, 0, stream>>>(pooled, cnt, Wmu, bmu, Wlv, blv, (float*)d_out);
}

// Round 4
// 369.360 us; speedup vs baseline: 1.9790x; 1.1417x over previous
//
#include <hip/hip_runtime.h>

// Problem constants (from the reference file)
#define N_NODES 50000
#define N_EDGES 800000
#define F_IN_D  128
#define H_DIM   256
#define L_DIM   64
#define G_NUM   500

typedef unsigned int   u32;
typedef unsigned short u16;
typedef __attribute__((ext_vector_type(8))) short short8;
typedef __attribute__((ext_vector_type(4))) float f32x4;

static __device__ __forceinline__ float bf2f(u16 u) {
    union { u32 i; float f; } x; x.i = ((u32)u) << 16; return x.f;
}
static __device__ __forceinline__ u16 f2bf(float f) {
    union { float f; u32 i; } x; x.f = f;
    u32 r = (x.i + 0x7fffu + ((x.i >> 16) & 1u)) >> 16;
    return (u16)r;
}

// B-swizzle address (in u16 units): fragment layout for mfma_16x16x32_bf16.
// frag id = ((n0g*KS + k0i)*2 + plane)*4 + nt ; lane = lq*16 + lr ; j in short8
static __device__ __forceinline__ u32 bswz_idx(int n, int k, int plane, int KS) {
    int n0g = n >> 6, nt = (n >> 4) & 3, lr = n & 15;
    int k0i = k >> 5, ks = k & 31, lq = ks >> 3, j = ks & 7;
    return ((u32)((((n0g * KS + k0i) * 2 + plane) * 4 + nt) * 64 + lq * 16 + lr)) * 8 + j;
}

// ---------------------------------------------------------------------------
// Graph preprocessing
// ---------------------------------------------------------------------------
__global__ void init_kernel(int* __restrict__ hist, int* __restrict__ cnt,
                            float* __restrict__ pooled) {
    int i = blockIdx.x * 256 + threadIdx.x;
    if (i < N_NODES) hist[i] = 0;
    if (i < G_NUM)   cnt[i]  = 0;
    if (i < G_NUM * H_DIM) pooled[i] = 0.f;
}

__global__ void count_kernel(const int* __restrict__ dst, const int* __restrict__ batch,
                             int* __restrict__ hist, int* __restrict__ cnt) {
    int i = blockIdx.x * 256 + threadIdx.x;
    if (i < N_EDGES) atomicAdd(&hist[dst[i]], 1);
    if (i < N_NODES) atomicAdd(&cnt[batch[i]], 1);
}

// exclusive scan of hist (chunk=256) + fused dinv computation
__global__ void scan_chunk_kernel(const int* __restrict__ in, int* __restrict__ excl,
                                  int* __restrict__ partials, float* __restrict__ dinv, int n) {
    __shared__ int sm[256];
    int t = threadIdx.x;
    int i = blockIdx.x * 256 + t;
    int v = (i < n) ? in[i] : 0;
    sm[t] = v; __syncthreads();
    for (int off = 1; off < 256; off <<= 1) {
        int x = (t >= off) ? sm[t - off] : 0;
        __syncthreads();
        sm[t] += x;
        __syncthreads();
    }
    if (i < n) {
        excl[i] = sm[t] - v;
        dinv[i] = 1.0f / sqrtf((float)(v + 1));   // +1 self loop
    }
    if (t == 255) partials[blockIdx.x] = sm[255];
}

__global__ void scan_part_kernel(int* __restrict__ partials, int nb, int* __restrict__ total_out) {
    __shared__ int sm[256];
    int t = threadIdx.x;
    int v = (t < nb) ? partials[t] : 0;
    sm[t] = v; __syncthreads();
    for (int off = 1; off < 256; off <<= 1) {
        int x = (t >= off) ? sm[t - off] : 0;
        __syncthreads();
        sm[t] += x;
        __syncthreads();
    }
    if (t < nb) partials[t] = sm[t] - v;
    if (t == 255) *total_out = sm[255];
}

__global__ void scan_final_kernel(const int* __restrict__ excl, const int* __restrict__ partials,
                                  int* __restrict__ out, int* __restrict__ cursor, int n) {
    int i = blockIdx.x * 256 + threadIdx.x;
    if (i < n) {
        int v = excl[i] + partials[blockIdx.x];
        out[i] = v;
        cursor[i] = v;
    }
}

// CSR entries packed (src, bits(dinv[src]))
__global__ void place_kernel(const int* __restrict__ src, const int* __restrict__ dst,
                             const float* __restrict__ dinv,
                             int* __restrict__ cursor, uint2* __restrict__ csr) {
    int e = blockIdx.x * 256 + threadIdx.x;
    if (e < N_EDGES) {
        int s = src[e];
        int d = dst[e];
        int pos = atomicAdd(&cursor[d], 1);
        csr[pos] = make_uint2((u32)s, __float_as_uint(dinv[s]));
    }
}

// ---------------------------------------------------------------------------
// All dtype conversions in one launch:
//  seg0: x fp32 -> xb bf16
//  seg1: W1 [128][256] -> w1swz (hi/lo planes, MFMA-fragment swizzled)
//  seg2: W2 [256][256] -> w2swz
// ---------------------------------------------------------------------------
#define NXQ (N_NODES * F_IN_D / 4)          // 1,600,000
#define NW1 (F_IN_D * H_DIM)                // 32,768
#define NW2 (H_DIM * H_DIM)                 // 65,536
__global__ void conv_kernel(const float* __restrict__ x, u16* __restrict__ xb,
                            const float* __restrict__ W1, u16* __restrict__ w1swz,
                            const float* __restrict__ W2, u16* __restrict__ w2swz) {
    int i = blockIdx.x * 256 + threadIdx.x;
    if (i < NXQ) {
        float4 v = *(const float4*)&x[(size_t)i * 4];
        ushort4 o;
        o.x = f2bf(v.x); o.y = f2bf(v.y); o.z = f2bf(v.z); o.w = f2bf(v.w);
        *(ushort4*)&xb[(size_t)i * 4] = o;
    } else if (i < NXQ + NW1) {
        int idx = i - NXQ;
        int k = idx >> 8, n = idx & 255;
        float w = W1[idx];
        u16 h = f2bf(w);
        w1swz[bswz_idx(n, k, 0, F_IN_D / 32)] = h;
        w1swz[bswz_idx(n, k, 1, F_IN_D / 32)] = f2bf(w - bf2f(h));
    } else if (i < NXQ + NW1 + NW2) {
        int idx = i - NXQ - NW1;
        int k = idx >> 8, n = idx & 255;
        float w = W2[idx];
        u16 h = f2bf(w);
        w2swz[bswz_idx(n, k, 0, H_DIM / 32)] = h;
        w2swz[bswz_idx(n, k, 1, H_DIM / 32)] = f2bf(w - bf2f(h));
    }
}

// ---------------------------------------------------------------------------
// GCN aggregation, bf16 in -> bf16 out. One wave per node, edge loop
// unrolled x4 (4 gathers in flight).
// ---------------------------------------------------------------------------
__global__ __launch_bounds__(256)
void agg128_kernel(const u16* __restrict__ In, const float* __restrict__ dinv,
                   const int* __restrict__ rp, const uint2* __restrict__ csr,
                   u16* __restrict__ Out) {
    int node = blockIdx.x * 4 + (threadIdx.x >> 6);
    int lane = threadIdx.x & 63;
    if (node >= N_NODES) return;
    int c = lane * 2;
    float di = dinv[node];
    int r0 = rp[node], r1 = rp[node + 1];
    u32 sv = *(const u32*)&In[(size_t)node * 128 + c];
    float a0 = di * bf2f((u16)(sv & 0xffff));
    float a1 = di * bf2f((u16)(sv >> 16));
    int j = r0;
    for (; j + 4 <= r1; j += 4) {
        uint2 e0 = csr[j], e1 = csr[j + 1], e2 = csr[j + 2], e3 = csr[j + 3];
        u32 v0 = *(const u32*)&In[(size_t)e0.x * 128 + c];
        u32 v1 = *(const u32*)&In[(size_t)e1.x * 128 + c];
        u32 v2 = *(const u32*)&In[(size_t)e2.x * 128 + c];
        u32 v3 = *(const u32*)&In[(size_t)e3.x * 128 + c];
        float w0 = __uint_as_float(e0.y), w1 = __uint_as_float(e1.y);
        float w2 = __uint_as_float(e2.y), w3 = __uint_as_float(e3.y);
        a0 = fmaf(w0, bf2f((u16)(v0 & 0xffff)), a0);
        a1 = fmaf(w0, bf2f((u16)(v0 >> 16)), a1);
        a0 = fmaf(w1, bf2f((u16)(v1 & 0xffff)), a0);
        a1 = fmaf(w1, bf2f((u16)(v1 >> 16)), a1);
        a0 = fmaf(w2, bf2f((u16)(v2 & 0xffff)), a0);
        a1 = fmaf(w2, bf2f((u16)(v2 >> 16)), a1);
        a0 = fmaf(w3, bf2f((u16)(v3 & 0xffff)), a0);
        a1 = fmaf(w3, bf2f((u16)(v3 >> 16)), a1);
    }
    for (; j < r1; ++j) {
        uint2 e = csr[j];
        u32 v = *(const u32*)&In[(size_t)e.x * 128 + c];
        float w = __uint_as_float(e.y);
        a0 = fmaf(w, bf2f((u16)(v & 0xffff)), a0);
        a1 = fmaf(w, bf2f((u16)(v >> 16)), a1);
    }
    u32 o = ((u32)f2bf(di * a1) << 16) | (u32)f2bf(di * a0);
    *(u32*)&Out[(size_t)node * 128 + c] = o;
}

__global__ __launch_bounds__(256)
void agg256_kernel(const u16* __restrict__ In, const float* __restrict__ dinv,
                   const int* __restrict__ rp, const uint2* __restrict__ csr,
                   u16* __restrict__ Out) {
    int node = blockIdx.x * 4 + (threadIdx.x >> 6);
    int lane = threadIdx.x & 63;
    if (node >= N_NODES) return;
    int c = lane * 4;
    float di = dinv[node];
    int r0 = rp[node], r1 = rp[node + 1];
    uint2 sv = *(const uint2*)&In[(size_t)node * 256 + c];
    float a0 = di * bf2f((u16)(sv.x & 0xffff));
    float a1 = di * bf2f((u16)(sv.x >> 16));
    float a2 = di * bf2f((u16)(sv.y & 0xffff));
    float a3 = di * bf2f((u16)(sv.y >> 16));
    int j = r0;
    for (; j + 4 <= r1; j += 4) {
        uint2 e0 = csr[j], e1 = csr[j + 1], e2 = csr[j + 2], e3 = csr[j + 3];
        uint2 v0 = *(const uint2*)&In[(size_t)e0.x * 256 + c];
        uint2 v1 = *(const uint2*)&In[(size_t)e1.x * 256 + c];
        uint2 v2 = *(const uint2*)&In[(size_t)e2.x * 256 + c];
        uint2 v3 = *(const uint2*)&In[(size_t)e3.x * 256 + c];
        float w0 = __uint_as_float(e0.y), w1 = __uint_as_float(e1.y);
        float w2 = __uint_as_float(e2.y), w3 = __uint_as_float(e3.y);
        a0 = fmaf(w0, bf2f((u16)(v0.x & 0xffff)), a0);
        a1 = fmaf(w0, bf2f((u16)(v0.x >> 16)), a1);
        a2 = fmaf(w0, bf2f((u16)(v0.y & 0xffff)), a2);
        a3 = fmaf(w0, bf2f((u16)(v0.y >> 16)), a3);
        a0 = fmaf(w1, bf2f((u16)(v1.x & 0xffff)), a0);
        a1 = fmaf(w1, bf2f((u16)(v1.x >> 16)), a1);
        a2 = fmaf(w1, bf2f((u16)(v1.y & 0xffff)), a2);
        a3 = fmaf(w1, bf2f((u16)(v1.y >> 16)), a3);
        a0 = fmaf(w2, bf2f((u16)(v2.x & 0xffff)), a0);
        a1 = fmaf(w2, bf2f((u16)(v2.x >> 16)), a1);
        a2 = fmaf(w2, bf2f((u16)(v2.y & 0xffff)), a2);
        a3 = fmaf(w2, bf2f((u16)(v2.y >> 16)), a3);
        a0 = fmaf(w3, bf2f((u16)(v3.x & 0xffff)), a0);
        a1 = fmaf(w3, bf2f((u16)(v3.x >> 16)), a1);
        a2 = fmaf(w3, bf2f((u16)(v3.y & 0xffff)), a2);
        a3 = fmaf(w3, bf2f((u16)(v3.y >> 16)), a3);
    }
    for (; j < r1; ++j) {
        uint2 e = csr[j];
        uint2 v = *(const uint2*)&In[(size_t)e.x * 256 + c];
        float w = __uint_as_float(e.y);
        a0 = fmaf(w, bf2f((u16)(v.x & 0xffff)), a0);
        a1 = fmaf(w, bf2f((u16)(v.x >> 16)), a1);
        a2 = fmaf(w, bf2f((u16)(v.y & 0xffff)), a2);
        a3 = fmaf(w, bf2f((u16)(v.y >> 16)), a3);
    }
    uint2 o;
    o.x = ((u32)f2bf(di * a1) << 16) | (u32)f2bf(di * a0);
    o.y = ((u32)f2bf(di * a3) << 16) | (u32)f2bf(di * a2);
    *(uint2*)&Out[(size_t)node * 256 + c] = o;
}

// ---------------------------------------------------------------------------
// MFMA GEMM layer 1: H1[M,256] = relu( A[M,128] @ W1 + b1 ), bf16 out.
// 64 rows x 256 cols per block; wave w = cols w*64..+64; mt=4, nt=4.
// B pre-swizzled: every B-frag load is one contiguous 1 KB segment.
// ---------------------------------------------------------------------------
template<int K>
__global__ __launch_bounds__(256, 3)
void gemm1_kernel(const u16* __restrict__ A, const short8* __restrict__ Bswz,
                  const float* __restrict__ bias, u16* __restrict__ Out, int M) {
    const int KS = K / 32;
    __shared__ u16 cst[64][264];
    int tid  = threadIdx.x;
    int wave = tid >> 6, lane = tid & 63;
    int m0 = blockIdx.x * 64;
    int n0 = wave * 64;
    int lr = lane & 15;
    int lk = (lane >> 4) * 8;

    f32x4 acc[4][4];
#pragma unroll
    for (int i = 0; i < 4; ++i)
#pragma unroll
        for (int j = 0; j < 4; ++j) acc[i][j] = {0.f, 0.f, 0.f, 0.f};

    for (int k0i = 0; k0i < KS; ++k0i) {
        int k0 = k0i * 32;
        short8 a[4], bh[4], bl[4];
#pragma unroll
        for (int mt = 0; mt < 4; ++mt) {
            int m = m0 + mt * 16 + lr;
            if (m > M - 1) m = M - 1;
            a[mt] = *(const short8*)&A[(size_t)m * K + k0 + lk];
        }
        const short8* bp = Bswz + ((size_t)(wave * KS + k0i) * 8) * 64 + lane;
#pragma unroll
        for (int nt = 0; nt < 4; ++nt) {
            bh[nt] = bp[(size_t)nt * 64];
            bl[nt] = bp[(size_t)(4 + nt) * 64];
        }
#pragma unroll
        for (int mt = 0; mt < 4; ++mt)
#pragma unroll
            for (int nt = 0; nt < 4; ++nt) {
                acc[mt][nt] = __builtin_amdgcn_mfma_f32_16x16x32_bf16(a[mt], bh[nt], acc[mt][nt], 0, 0, 0);
                acc[mt][nt] = __builtin_amdgcn_mfma_f32_16x16x32_bf16(a[mt], bl[nt], acc[mt][nt], 0, 0, 0);
            }
    }

#pragma unroll
    for (int mt = 0; mt < 4; ++mt)
#pragma unroll
        for (int nt = 0; nt < 4; ++nt) {
            int col = n0 + nt * 16 + lr;
            float b = bias[col];
#pragma unroll
            for (int r = 0; r < 4; ++r) {
                int row = mt * 16 + (lane >> 4) * 4 + r;
                cst[row][col] = f2bf(fmaxf(acc[mt][nt][r] + b, 0.f));
            }
        }
    __syncthreads();
#pragma unroll
    for (int p = 0; p < 8; ++p) {
        int row = p * 8 + (tid >> 5);
        int c16 = (tid & 31) * 8;
        int m = m0 + row;
        if (m < M) {
            uint4 v = *(const uint4*)&cst[row][c16];
            *(uint4*)&Out[(size_t)m * 256 + c16] = v;
        }
    }
}

// ---------------------------------------------------------------------------
// MFMA GEMM layer 2 + fused mean-pool: H2 rows live only in LDS (bf16),
// segment-summed into pooled[] (batch sorted).
// ---------------------------------------------------------------------------
__global__ __launch_bounds__(256, 3)
void gemm2_pool_kernel(const u16* __restrict__ A, const short8* __restrict__ Bswz,
                       const float* __restrict__ bias, const int* __restrict__ batch,
                       float* __restrict__ pooled, int M) {
    const int K = H_DIM, KS = K / 32;
    __shared__ u16 cst[64][264];
    __shared__ int batch_s[64];
    int tid  = threadIdx.x;
    int wave = tid >> 6, lane = tid & 63;
    int m0 = blockIdx.x * 64;
    int n0 = wave * 64;
    int lr = lane & 15;
    int lk = (lane >> 4) * 8;

    f32x4 acc[4][4];
#pragma unroll
    for (int i = 0; i < 4; ++i)
#pragma unroll
        for (int j = 0; j < 4; ++j) acc[i][j] = {0.f, 0.f, 0.f, 0.f};

    for (int k0i = 0; k0i < KS; ++k0i) {
        int k0 = k0i * 32;
        short8 a[4], bh[4], bl[4];
#pragma unroll
        for (int mt = 0; mt < 4; ++mt) {
            int m = m0 + mt * 16 + lr;
            if (m > M - 1) m = M - 1;
            a[mt] = *(const short8*)&A[(size_t)m * K + k0 + lk];
        }
        const short8* bp = Bswz + ((size_t)(wave * KS + k0i) * 8) * 64 + lane;
#pragma unroll
        for (int nt = 0; nt < 4; ++nt) {
            bh[nt] = bp[(size_t)nt * 64];
            bl[nt] = bp[(size_t)(4 + nt) * 64];
        }
#pragma unroll
        for (int mt = 0; mt < 4; ++mt)
#pragma unroll
            for (int nt = 0; nt < 4; ++nt) {
                acc[mt][nt] = __builtin_amdgcn_mfma_f32_16x16x32_bf16(a[mt], bh[nt], acc[mt][nt], 0, 0, 0);
                acc[mt][nt] = __builtin_amdgcn_mfma_f32_16x16x32_bf16(a[mt], bl[nt], acc[mt][nt], 0, 0, 0);
            }
    }

    if (tid < 64) {
        int m = m0 + tid;
        batch_s[tid] = (m < M) ? batch[m] : -1;
    }
#pragma unroll
    for (int mt = 0; mt < 4; ++mt)
#pragma unroll
        for (int nt = 0; nt < 4; ++nt) {
            int col = n0 + nt * 16 + lr;
            float b = bias[col];
#pragma unroll
            for (int r = 0; r < 4; ++r) {
                int row = mt * 16 + (lane >> 4) * 4 + r;
                cst[row][col] = f2bf(fmaxf(acc[mt][nt][r] + b, 0.f));
            }
        }
    __syncthreads();

    // segmented pooling: thread = column, walk the 64 sorted rows
    int rows = M - m0; if (rows > 64) rows = 64;
    float s = 0.f;
    int gp = batch_s[0];
    for (int r = 0; r < rows; ++r) {
        int g = batch_s[r];
        if (g != gp) {
            atomicAdd(&pooled[(size_t)gp * H_DIM + tid], s);
            s = 0.f;
            gp = g;
        }
        s += bf2f(cst[r][tid]);
    }
    atomicAdd(&pooled[(size_t)gp * H_DIM + tid], s);
}

// ---------------------------------------------------------------------------
// Heads (fp32): h_graph = pooled/cnt; mu/logvar = h_graph @ W + b
// ---------------------------------------------------------------------------
__global__ void head_kernel(const float* __restrict__ pooled, const int* __restrict__ cnt,
                            const float* __restrict__ Wmu, const float* __restrict__ bmu,
                            const float* __restrict__ Wlv, const float* __restrict__ blv,
                            float* __restrict__ out) {
    __shared__ float hg[H_DIM];
    int g = blockIdx.x, l = threadIdx.x;   // 64 threads
    float inv = 1.0f / fmaxf((float)cnt[g], 1.0f);
    for (int k = l; k < H_DIM; k += 64) hg[k] = pooled[(size_t)g * H_DIM + k] * inv;
    __syncthreads();
    float mu = bmu[l], lv = blv[l];
    for (int k = 0; k < H_DIM; ++k) {
        float h = hg[k];
        mu = fmaf(h, Wmu[k * L_DIM + l], mu);
        lv = fmaf(h, Wlv[k * L_DIM + l], lv);
    }
    out[(size_t)g * L_DIM + l] = mu;
    out[(size_t)G_NUM * L_DIM + (size_t)g * L_DIM + l] = lv;
}

// ---------------------------------------------------------------------------
extern "C" void kernel_launch(void* const* d_in, const int* in_sizes, int n_in,
                              void* d_out, int out_size, void* d_ws, size_t ws_size,
                              hipStream_t stream) {
    const float* x     = (const float*)d_in[0];
    const int*   ei    = (const int*)  d_in[1];
    const int*   batch = (const int*)  d_in[2];
    const float* W1  = (const float*)d_in[4];
    const float* b1  = (const float*)d_in[5];
    const float* W2  = (const float*)d_in[6];
    const float* b2  = (const float*)d_in[7];
    const float* Wmu = (const float*)d_in[8];
    const float* bmu = (const float*)d_in[9];
    const float* Wlv = (const float*)d_in[10];
    const float* blv = (const float*)d_in[11];
    const int* src = ei;
    const int* dst = ei + N_EDGES;

    char* ws = (char*)d_ws;
    size_t off = 0;
    auto alloc = [&](size_t bytes) -> void* {
        void* p = ws + off;
        off += (bytes + 255) & ~(size_t)255;
        return p;
    };
    int*   hist     = (int*)alloc((size_t)N_NODES * 4);
    int*   cnt      = (int*)alloc((size_t)G_NUM * 4);
    float* dinv     = (float*)alloc((size_t)N_NODES * 4);
    int*   row_ptr  = (int*)alloc((size_t)(N_NODES + 1) * 4);
    int*   cursor   = (int*)alloc((size_t)N_NODES * 4);
    uint2* csr      = (uint2*)alloc((size_t)N_EDGES * 8);
    int*   excl     = (int*)alloc((size_t)N_NODES * 4);
    int*   partials = (int*)alloc(256 * 4);
    u16*   xb    = (u16*)alloc((size_t)N_NODES * F_IN_D * 2);  // 12.8 MB
    u16*   Xa    = (u16*)alloc((size_t)N_NODES * F_IN_D * 2);  // 12.8 MB
    u16*   H1    = (u16*)alloc((size_t)N_NODES * H_DIM * 2);   // 25.6 MB
    u16*   Ha    = (u16*)alloc((size_t)N_NODES * H_DIM * 2);   // 25.6 MB
    u16*   w1swz = (u16*)alloc((size_t)2 * F_IN_D * H_DIM * 2);
    u16*   w2swz = (u16*)alloc((size_t)2 * H_DIM * H_DIM * 2);
    float* pooled = (float*)alloc((size_t)G_NUM * H_DIM * 4);
    (void)ws_size; (void)n_in; (void)in_sizes; (void)out_size;

    const int NB_SCAN = (N_NODES + 255) / 256;   // 196
    const int GEMM_NB = (N_NODES + 63) / 64;     // 782

    init_kernel <<<512, 256, 0, stream>>>(hist, cnt, pooled);
    count_kernel<<<(N_EDGES + 255) / 256, 256, 0, stream>>>(dst, batch, hist, cnt);
    scan_chunk_kernel<<<NB_SCAN, 256, 0, stream>>>(hist, excl, partials, dinv, N_NODES);
    scan_part_kernel <<<1, 256, 0, stream>>>(partials, NB_SCAN, row_ptr + N_NODES);
    scan_final_kernel<<<NB_SCAN, 256, 0, stream>>>(excl, partials, row_ptr, cursor, N_NODES);
    place_kernel<<<(N_EDGES + 255) / 256, 256, 0, stream>>>(src, dst, dinv, cursor, csr);
    conv_kernel <<<(NXQ + NW1 + NW2 + 255) / 256, 256, 0, stream>>>(x, xb, W1, w1swz, W2, w2swz);

    // layer 1: aggregate(x) then GEMM  (A_hat (X W) == (A_hat X) W)
    agg128_kernel<<<(N_NODES + 3) / 4, 256, 0, stream>>>(xb, dinv, row_ptr, csr, Xa);
    gemm1_kernel<F_IN_D><<<GEMM_NB, 256, 0, stream>>>(Xa, (const short8*)w1swz, b1, H1, N_NODES);
    // layer 2: aggregate(H1) then GEMM with fused mean-pool
    agg256_kernel<<<(N_NODES + 3) / 4, 256, 0, stream>>>(H1, dinv, row_ptr, csr, Ha);
    gemm2_pool_kernel<<<GEMM_NB, 256, 0, stream>>>(Ha, (const short8*)w2swz, b2, batch, pooled, N_NODES);

    head_kernel<<<G_NUM, 64, 0, stream>>>(pooled, cnt, Wmu, bmu, Wlv, blv, (float*)d_out);
}

// Round 5
// 345.835 us; speedup vs baseline: 2.1136x; 1.0680x over previous
//
#include <hip/hip_runtime.h>

// Problem constants (from the reference file)
#define N_NODES 50000
#define N_EDGES 800000
#define F_IN_D  128
#define H_DIM   256
#define L_DIM   64
#define G_NUM   500

typedef unsigned int   u32;
typedef unsigned short u16;
typedef __attribute__((ext_vector_type(8))) short short8;
typedef __attribute__((ext_vector_type(4))) float f32x4;

static __device__ __forceinline__ float bf2f(u16 u) {
    union { u32 i; float f; } x; x.i = ((u32)u) << 16; return x.f;
}
static __device__ __forceinline__ u16 f2bf(float f) {
    union { float f; u32 i; } x; x.f = f;
    u32 r = (x.i + 0x7fffu + ((x.i >> 16) & 1u)) >> 16;
    return (u16)r;
}

// B-swizzle address (in u16 units): fragment layout for mfma_16x16x32_bf16.
static __device__ __forceinline__ u32 bswz_idx(int n, int k, int plane, int KS) {
    int n0g = n >> 6, nt = (n >> 4) & 3, lr = n & 15;
    int k0i = k >> 5, ks = k & 31, lq = ks >> 3, j = ks & 7;
    return ((u32)((((n0g * KS + k0i) * 2 + plane) * 4 + nt) * 64 + lq * 16 + lr)) * 8 + j;
}

// ---------------------------------------------------------------------------
// Graph preprocessing
// ---------------------------------------------------------------------------
__global__ void init_kernel(int* __restrict__ hist, float* __restrict__ pooled) {
    int i = blockIdx.x * 256 + threadIdx.x;
    if (i < N_NODES) hist[i] = 0;
    if (i < G_NUM * H_DIM) pooled[i] = 0.f;
}

// degree histogram only — random-address atomics parallelize across channels.
// (cnt atomics removed: sorted batch made them a serial same-address stream.)
__global__ void count_kernel(const int* __restrict__ dst, int* __restrict__ hist) {
    int i = blockIdx.x * 256 + threadIdx.x;
    if (i < N_EDGES) atomicAdd(&hist[dst[i]], 1);
}

// batch is sorted: graph start offsets via boundary detection, no atomics.
// goff[g] = first i with batch[i] >= g ; goff[G_NUM] = N_NODES
__global__ void bounds_kernel(const int* __restrict__ batch, int* __restrict__ goff) {
    int i = blockIdx.x * 256 + threadIdx.x;
    if (i >= N_NODES) return;
    int b = batch[i];
    if (i == 0) {
        for (int g = 0; g <= b; ++g) goff[g] = 0;
    } else {
        int p = batch[i - 1];
        for (int g = p + 1; g <= b; ++g) goff[g] = i;
    }
    if (i == N_NODES - 1) {
        for (int g = b + 1; g <= G_NUM; ++g) goff[g] = N_NODES;
    }
}

// exclusive scan of hist (chunk=256) + fused dinv computation
__global__ void scan_chunk_kernel(const int* __restrict__ in, int* __restrict__ excl,
                                  int* __restrict__ partials, float* __restrict__ dinv, int n) {
    __shared__ int sm[256];
    int t = threadIdx.x;
    int i = blockIdx.x * 256 + t;
    int v = (i < n) ? in[i] : 0;
    sm[t] = v; __syncthreads();
    for (int off = 1; off < 256; off <<= 1) {
        int x = (t >= off) ? sm[t - off] : 0;
        __syncthreads();
        sm[t] += x;
        __syncthreads();
    }
    if (i < n) {
        excl[i] = sm[t] - v;
        dinv[i] = 1.0f / sqrtf((float)(v + 1));   // +1 self loop
    }
    if (t == 255) partials[blockIdx.x] = sm[255];
}

__global__ void scan_part_kernel(int* __restrict__ partials, int nb, int* __restrict__ total_out) {
    __shared__ int sm[256];
    int t = threadIdx.x;
    int v = (t < nb) ? partials[t] : 0;
    sm[t] = v; __syncthreads();
    for (int off = 1; off < 256; off <<= 1) {
        int x = (t >= off) ? sm[t - off] : 0;
        __syncthreads();
        sm[t] += x;
        __syncthreads();
    }
    if (t < nb) partials[t] = sm[t] - v;
    if (t == 255) *total_out = sm[255];
}

__global__ void scan_final_kernel(const int* __restrict__ excl, const int* __restrict__ partials,
                                  int* __restrict__ out, int* __restrict__ cursor, int n) {
    int i = blockIdx.x * 256 + threadIdx.x;
    if (i < n) {
        int v = excl[i] + partials[blockIdx.x];
        out[i] = v;
        cursor[i] = v;
    }
}

// CSR entries packed (src, bits(dinv[src]))
__global__ void place_kernel(const int* __restrict__ src, const int* __restrict__ dst,
                             const float* __restrict__ dinv,
                             int* __restrict__ cursor, uint2* __restrict__ csr) {
    int e = blockIdx.x * 256 + threadIdx.x;
    if (e < N_EDGES) {
        int s = src[e];
        int d = dst[e];
        int pos = atomicAdd(&cursor[d], 1);
        csr[pos] = make_uint2((u32)s, __float_as_uint(dinv[s]));
    }
}

// ---------------------------------------------------------------------------
// All dtype conversions in one launch
// ---------------------------------------------------------------------------
#define NXQ (N_NODES * F_IN_D / 4)          // 1,600,000
#define NW1 (F_IN_D * H_DIM)                // 32,768
#define NW2 (H_DIM * H_DIM)                 // 65,536
__global__ void conv_kernel(const float* __restrict__ x, u16* __restrict__ xb,
                            const float* __restrict__ W1, u16* __restrict__ w1swz,
                            const float* __restrict__ W2, u16* __restrict__ w2swz) {
    int i = blockIdx.x * 256 + threadIdx.x;
    if (i < NXQ) {
        float4 v = *(const float4*)&x[(size_t)i * 4];
        ushort4 o;
        o.x = f2bf(v.x); o.y = f2bf(v.y); o.z = f2bf(v.z); o.w = f2bf(v.w);
        *(ushort4*)&xb[(size_t)i * 4] = o;
    } else if (i < NXQ + NW1) {
        int idx = i - NXQ;
        int k = idx >> 8, n = idx & 255;
        float w = W1[idx];
        u16 h = f2bf(w);
        w1swz[bswz_idx(n, k, 0, F_IN_D / 32)] = h;
        w1swz[bswz_idx(n, k, 1, F_IN_D / 32)] = f2bf(w - bf2f(h));
    } else if (i < NXQ + NW1 + NW2) {
        int idx = i - NXQ - NW1;
        int k = idx >> 8, n = idx & 255;
        float w = W2[idx];
        u16 h = f2bf(w);
        w2swz[bswz_idx(n, k, 0, H_DIM / 32)] = h;
        w2swz[bswz_idx(n, k, 1, H_DIM / 32)] = f2bf(w - bf2f(h));
    }
}

// ---------------------------------------------------------------------------
// GCN aggregation, bf16 in -> bf16 out. One wave per node, edge loop x4.
// ---------------------------------------------------------------------------
__global__ __launch_bounds__(256)
void agg128_kernel(const u16* __restrict__ In, const float* __restrict__ dinv,
                   const int* __restrict__ rp, const uint2* __restrict__ csr,
                   u16* __restrict__ Out) {
    int node = blockIdx.x * 4 + (threadIdx.x >> 6);
    int lane = threadIdx.x & 63;
    if (node >= N_NODES) return;
    int c = lane * 2;
    float di = dinv[node];
    int r0 = rp[node], r1 = rp[node + 1];
    u32 sv = *(const u32*)&In[(size_t)node * 128 + c];
    float a0 = di * bf2f((u16)(sv & 0xffff));
    float a1 = di * bf2f((u16)(sv >> 16));
    int j = r0;
    for (; j + 4 <= r1; j += 4) {
        uint2 e0 = csr[j], e1 = csr[j + 1], e2 = csr[j + 2], e3 = csr[j + 3];
        u32 v0 = *(const u32*)&In[(size_t)e0.x * 128 + c];
        u32 v1 = *(const u32*)&In[(size_t)e1.x * 128 + c];
        u32 v2 = *(const u32*)&In[(size_t)e2.x * 128 + c];
        u32 v3 = *(const u32*)&In[(size_t)e3.x * 128 + c];
        float w0 = __uint_as_float(e0.y), w1 = __uint_as_float(e1.y);
        float w2 = __uint_as_float(e2.y), w3 = __uint_as_float(e3.y);
        a0 = fmaf(w0, bf2f((u16)(v0 & 0xffff)), a0);
        a1 = fmaf(w0, bf2f((u16)(v0 >> 16)), a1);
        a0 = fmaf(w1, bf2f((u16)(v1 & 0xffff)), a0);
        a1 = fmaf(w1, bf2f((u16)(v1 >> 16)), a1);
        a0 = fmaf(w2, bf2f((u16)(v2 & 0xffff)), a0);
        a1 = fmaf(w2, bf2f((u16)(v2 >> 16)), a1);
        a0 = fmaf(w3, bf2f((u16)(v3 & 0xffff)), a0);
        a1 = fmaf(w3, bf2f((u16)(v3 >> 16)), a1);
    }
    for (; j < r1; ++j) {
        uint2 e = csr[j];
        u32 v = *(const u32*)&In[(size_t)e.x * 128 + c];
        float w = __uint_as_float(e.y);
        a0 = fmaf(w, bf2f((u16)(v & 0xffff)), a0);
        a1 = fmaf(w, bf2f((u16)(v >> 16)), a1);
    }
    u32 o = ((u32)f2bf(di * a1) << 16) | (u32)f2bf(di * a0);
    *(u32*)&Out[(size_t)node * 128 + c] = o;
}

__global__ __launch_bounds__(256)
void agg256_kernel(const u16* __restrict__ In, const float* __restrict__ dinv,
                   const int* __restrict__ rp, const uint2* __restrict__ csr,
                   u16* __restrict__ Out) {
    int node = blockIdx.x * 4 + (threadIdx.x >> 6);
    int lane = threadIdx.x & 63;
    if (node >= N_NODES) return;
    int c = lane * 4;
    float di = dinv[node];
    int r0 = rp[node], r1 = rp[node + 1];
    uint2 sv = *(const uint2*)&In[(size_t)node * 256 + c];
    float a0 = di * bf2f((u16)(sv.x & 0xffff));
    float a1 = di * bf2f((u16)(sv.x >> 16));
    float a2 = di * bf2f((u16)(sv.y & 0xffff));
    float a3 = di * bf2f((u16)(sv.y >> 16));
    int j = r0;
    for (; j + 4 <= r1; j += 4) {
        uint2 e0 = csr[j], e1 = csr[j + 1], e2 = csr[j + 2], e3 = csr[j + 3];
        uint2 v0 = *(const uint2*)&In[(size_t)e0.x * 256 + c];
        uint2 v1 = *(const uint2*)&In[(size_t)e1.x * 256 + c];
        uint2 v2 = *(const uint2*)&In[(size_t)e2.x * 256 + c];
        uint2 v3 = *(const uint2*)&In[(size_t)e3.x * 256 + c];
        float w0 = __uint_as_float(e0.y), w1 = __uint_as_float(e1.y);
        float w2 = __uint_as_float(e2.y), w3 = __uint_as_float(e3.y);
        a0 = fmaf(w0, bf2f((u16)(v0.x & 0xffff)), a0);
        a1 = fmaf(w0, bf2f((u16)(v0.x >> 16)), a1);
        a2 = fmaf(w0, bf2f((u16)(v0.y & 0xffff)), a2);
        a3 = fmaf(w0, bf2f((u16)(v0.y >> 16)), a3);
        a0 = fmaf(w1, bf2f((u16)(v1.x & 0xffff)), a0);
        a1 = fmaf(w1, bf2f((u16)(v1.x >> 16)), a1);
        a2 = fmaf(w1, bf2f((u16)(v1.y & 0xffff)), a2);
        a3 = fmaf(w1, bf2f((u16)(v1.y >> 16)), a3);
        a0 = fmaf(w2, bf2f((u16)(v2.x & 0xffff)), a0);
        a1 = fmaf(w2, bf2f((u16)(v2.x >> 16)), a1);
        a2 = fmaf(w2, bf2f((u16)(v2.y & 0xffff)), a2);
        a3 = fmaf(w2, bf2f((u16)(v2.y >> 16)), a3);
        a0 = fmaf(w3, bf2f((u16)(v3.x & 0xffff)), a0);
        a1 = fmaf(w3, bf2f((u16)(v3.x >> 16)), a1);
        a2 = fmaf(w3, bf2f((u16)(v3.y & 0xffff)), a2);
        a3 = fmaf(w3, bf2f((u16)(v3.y >> 16)), a3);
    }
    for (; j < r1; ++j) {
        uint2 e = csr[j];
        uint2 v = *(const uint2*)&In[(size_t)e.x * 256 + c];
        float w = __uint_as_float(e.y);
        a0 = fmaf(w, bf2f((u16)(v.x & 0xffff)), a0);
        a1 = fmaf(w, bf2f((u16)(v.x >> 16)), a1);
        a2 = fmaf(w, bf2f((u16)(v.y & 0xffff)), a2);
        a3 = fmaf(w, bf2f((u16)(v.y >> 16)), a3);
    }
    uint2 o;
    o.x = ((u32)f2bf(di * a1) << 16) | (u32)f2bf(di * a0);
    o.y = ((u32)f2bf(di * a3) << 16) | (u32)f2bf(di * a2);
    *(uint2*)&Out[(size_t)node * 256 + c] = o;
}

// ---------------------------------------------------------------------------
// MFMA GEMM layer 1: H1[M,256] = relu( A[M,128] @ W1 + b1 ), bf16 out.
// ---------------------------------------------------------------------------
template<int K>
__global__ __launch_bounds__(256, 3)
void gemm1_kernel(const u16* __restrict__ A, const short8* __restrict__ Bswz,
                  const float* __restrict__ bias, u16* __restrict__ Out, int M) {
    const int KS = K / 32;
    __shared__ u16 cst[64][264];
    int tid  = threadIdx.x;
    int wave = tid >> 6, lane = tid & 63;
    int m0 = blockIdx.x * 64;
    int n0 = wave * 64;
    int lr = lane & 15;
    int lk = (lane >> 4) * 8;

    f32x4 acc[4][4];
#pragma unroll
    for (int i = 0; i < 4; ++i)
#pragma unroll
        for (int j = 0; j < 4; ++j) acc[i][j] = {0.f, 0.f, 0.f, 0.f};

    for (int k0i = 0; k0i < KS; ++k0i) {
        int k0 = k0i * 32;
        short8 a[4], bh[4], bl[4];
#pragma unroll
        for (int mt = 0; mt < 4; ++mt) {
            int m = m0 + mt * 16 + lr;
            if (m > M - 1) m = M - 1;
            a[mt] = *(const short8*)&A[(size_t)m * K + k0 + lk];
        }
        const short8* bp = Bswz + ((size_t)(wave * KS + k0i) * 8) * 64 + lane;
#pragma unroll
        for (int nt = 0; nt < 4; ++nt) {
            bh[nt] = bp[(size_t)nt * 64];
            bl[nt] = bp[(size_t)(4 + nt) * 64];
        }
#pragma unroll
        for (int mt = 0; mt < 4; ++mt)
#pragma unroll
            for (int nt = 0; nt < 4; ++nt) {
                acc[mt][nt] = __builtin_amdgcn_mfma_f32_16x16x32_bf16(a[mt], bh[nt], acc[mt][nt], 0, 0, 0);
                acc[mt][nt] = __builtin_amdgcn_mfma_f32_16x16x32_bf16(a[mt], bl[nt], acc[mt][nt], 0, 0, 0);
            }
    }

#pragma unroll
    for (int mt = 0; mt < 4; ++mt)
#pragma unroll
        for (int nt = 0; nt < 4; ++nt) {
            int col = n0 + nt * 16 + lr;
            float b = bias[col];
#pragma unroll
            for (int r = 0; r < 4; ++r) {
                int row = mt * 16 + (lane >> 4) * 4 + r;
                cst[row][col] = f2bf(fmaxf(acc[mt][nt][r] + b, 0.f));
            }
        }
    __syncthreads();
#pragma unroll
    for (int p = 0; p < 8; ++p) {
        int row = p * 8 + (tid >> 5);
        int c16 = (tid & 31) * 8;
        int m = m0 + row;
        if (m < M) {
            uint4 v = *(const uint4*)&cst[row][c16];
            *(uint4*)&Out[(size_t)m * 256 + c16] = v;
        }
    }
}

// ---------------------------------------------------------------------------
// MFMA GEMM layer 2 + fused mean-pool
// ---------------------------------------------------------------------------
__global__ __launch_bounds__(256, 3)
void gemm2_pool_kernel(const u16* __restrict__ A, const short8* __restrict__ Bswz,
                       const float* __restrict__ bias, const int* __restrict__ batch,
                       float* __restrict__ pooled, int M) {
    const int K = H_DIM, KS = K / 32;
    __shared__ u16 cst[64][264];
    __shared__ int batch_s[64];
    int tid  = threadIdx.x;
    int wave = tid >> 6, lane = tid & 63;
    int m0 = blockIdx.x * 64;
    int n0 = wave * 64;
    int lr = lane & 15;
    int lk = (lane >> 4) * 8;

    f32x4 acc[4][4];
#pragma unroll
    for (int i = 0; i < 4; ++i)
#pragma unroll
        for (int j = 0; j < 4; ++j) acc[i][j] = {0.f, 0.f, 0.f, 0.f};

    for (int k0i = 0; k0i < KS; ++k0i) {
        int k0 = k0i * 32;
        short8 a[4], bh[4], bl[4];
#pragma unroll
        for (int mt = 0; mt < 4; ++mt) {
            int m = m0 + mt * 16 + lr;
            if (m > M - 1) m = M - 1;
            a[mt] = *(const short8*)&A[(size_t)m * K + k0 + lk];
        }
        const short8* bp = Bswz + ((size_t)(wave * KS + k0i) * 8) * 64 + lane;
#pragma unroll
        for (int nt = 0; nt < 4; ++nt) {
            bh[nt] = bp[(size_t)nt * 64];
            bl[nt] = bp[(size_t)(4 + nt) * 64];
        }
#pragma unroll
        for (int mt = 0; mt < 4; ++mt)
#pragma unroll
            for (int nt = 0; nt < 4; ++nt) {
                acc[mt][nt] = __builtin_amdgcn_mfma_f32_16x16x32_bf16(a[mt], bh[nt], acc[mt][nt], 0, 0, 0);
                acc[mt][nt] = __builtin_amdgcn_mfma_f32_16x16x32_bf16(a[mt], bl[nt], acc[mt][nt], 0, 0, 0);
            }
    }

    if (tid < 64) {
        int m = m0 + tid;
        batch_s[tid] = (m < M) ? batch[m] : -1;
    }
#pragma unroll
    for (int mt = 0; mt < 4; ++mt)
#pragma unroll
        for (int nt = 0; nt < 4; ++nt) {
            int col = n0 + nt * 16 + lr;
            float b = bias[col];
#pragma unroll
            for (int r = 0; r < 4; ++r) {
                int row = mt * 16 + (lane >> 4) * 4 + r;
                cst[row][col] = f2bf(fmaxf(acc[mt][nt][r] + b, 0.f));
            }
        }
    __syncthreads();

    // segmented pooling: thread = column, walk the 64 sorted rows
    int rows = M - m0; if (rows > 64) rows = 64;
    float s = 0.f;
    int gp = batch_s[0];
    for (int r = 0; r < rows; ++r) {
        int g = batch_s[r];
        if (g != gp) {
            atomicAdd(&pooled[(size_t)gp * H_DIM + tid], s);
            s = 0.f;
            gp = g;
        }
        s += bf2f(cst[r][tid]);
    }
    atomicAdd(&pooled[(size_t)gp * H_DIM + tid], s);
}

// ---------------------------------------------------------------------------
// Heads (fp32): h_graph = pooled/cnt (cnt from goff diffs); mu/logvar heads
// ---------------------------------------------------------------------------
__global__ void head_kernel(const float* __restrict__ pooled, const int* __restrict__ goff,
                            const float* __restrict__ Wmu, const float* __restrict__ bmu,
                            const float* __restrict__ Wlv, const float* __restrict__ blv,
                            float* __restrict__ out) {
    __shared__ float hg[H_DIM];
    int g = blockIdx.x, l = threadIdx.x;   // 64 threads
    float inv = 1.0f / fmaxf((float)(goff[g + 1] - goff[g]), 1.0f);
    for (int k = l; k < H_DIM; k += 64) hg[k] = pooled[(size_t)g * H_DIM + k] * inv;
    __syncthreads();
    float mu = bmu[l], lv = blv[l];
    for (int k = 0; k < H_DIM; ++k) {
        float h = hg[k];
        mu = fmaf(h, Wmu[k * L_DIM + l], mu);
        lv = fmaf(h, Wlv[k * L_DIM + l], lv);
    }
    out[(size_t)g * L_DIM + l] = mu;
    out[(size_t)G_NUM * L_DIM + (size_t)g * L_DIM + l] = lv;
}

// ---------------------------------------------------------------------------
extern "C" void kernel_launch(void* const* d_in, const int* in_sizes, int n_in,
                              void* d_out, int out_size, void* d_ws, size_t ws_size,
                              hipStream_t stream) {
    const float* x     = (const float*)d_in[0];
    const int*   ei    = (const int*)  d_in[1];
    const int*   batch = (const int*)  d_in[2];
    const float* W1  = (const float*)d_in[4];
    const float* b1  = (const float*)d_in[5];
    const float* W2  = (const float*)d_in[6];
    const float* b2  = (const float*)d_in[7];
    const float* Wmu = (const float*)d_in[8];
    const float* bmu = (const float*)d_in[9];
    const float* Wlv = (const float*)d_in[10];
    const float* blv = (const float*)d_in[11];
    const int* src = ei;
    const int* dst = ei + N_EDGES;

    char* ws = (char*)d_ws;
    size_t off = 0;
    auto alloc = [&](size_t bytes) -> void* {
        void* p = ws + off;
        off += (bytes + 255) & ~(size_t)255;
        return p;
    };
    int*   hist     = (int*)alloc((size_t)N_NODES * 4);
    float* dinv     = (float*)alloc((size_t)N_NODES * 4);
    int*   row_ptr  = (int*)alloc((size_t)(N_NODES + 1) * 4);
    int*   cursor   = (int*)alloc((size_t)N_NODES * 4);
    uint2* csr      = (uint2*)alloc((size_t)N_EDGES * 8);
    int*   excl     = (int*)alloc((size_t)N_NODES * 4);
    int*   partials = (int*)alloc(256 * 4);
    int*   goff     = (int*)alloc((size_t)(G_NUM + 1) * 4);
    u16*   xb    = (u16*)alloc((size_t)N_NODES * F_IN_D * 2);  // 12.8 MB
    u16*   Xa    = (u16*)alloc((size_t)N_NODES * F_IN_D * 2);  // 12.8 MB
    u16*   H1    = (u16*)alloc((size_t)N_NODES * H_DIM * 2);   // 25.6 MB
    u16*   Ha    = (u16*)alloc((size_t)N_NODES * H_DIM * 2);   // 25.6 MB
    u16*   w1swz = (u16*)alloc((size_t)2 * F_IN_D * H_DIM * 2);
    u16*   w2swz = (u16*)alloc((size_t)2 * H_DIM * H_DIM * 2);
    float* pooled = (float*)alloc((size_t)G_NUM * H_DIM * 4);
    (void)ws_size; (void)n_in; (void)in_sizes; (void)out_size;

    const int NB_SCAN = (N_NODES + 255) / 256;   // 196
    const int GEMM_NB = (N_NODES + 63) / 64;     // 782

    init_kernel <<<512, 256, 0, stream>>>(hist, pooled);
    count_kernel<<<(N_EDGES + 255) / 256, 256, 0, stream>>>(dst, hist);
    bounds_kernel<<<NB_SCAN, 256, 0, stream>>>(batch, goff);
    scan_chunk_kernel<<<NB_SCAN, 256, 0, stream>>>(hist, excl, partials, dinv, N_NODES);
    scan_part_kernel <<<1, 256, 0, stream>>>(partials, NB_SCAN, row_ptr + N_NODES);
    scan_final_kernel<<<NB_SCAN, 256, 0, stream>>>(excl, partials, row_ptr, cursor, N_NODES);
    place_kernel<<<(N_EDGES + 255) / 256, 256, 0, stream>>>(src, dst, dinv, cursor, csr);
    conv_kernel <<<(NXQ + NW1 + NW2 + 255) / 256, 256, 0, stream>>>(x, xb, W1, w1swz, W2, w2swz);

    // layer 1: aggregate(x) then GEMM  (A_hat (X W) == (A_hat X) W)
    agg128_kernel<<<(N_NODES + 3) / 4, 256, 0, stream>>>(xb, dinv, row_ptr, csr, Xa);
    gemm1_kernel<F_IN_D><<<GEMM_NB, 256, 0, stream>>>(Xa, (const short8*)w1swz, b1, H1, N_NODES);
    // layer 2: aggregate(H1) then GEMM with fused mean-pool
    agg256_kernel<<<(N_NODES + 3) / 4, 256, 0, stream>>>(H1, dinv, row_ptr, csr, Ha);
    gemm2_pool_kernel<<<GEMM_NB, 256, 0, stream>>>(Ha, (const short8*)w2swz, b2, batch, pooled, N_NODES);

    head_kernel<<<G_NUM, 64, 0, stream>>>(pooled, goff, Wmu, bmu, Wlv, blv, (float*)d_out);
}